// Round 1
// baseline (5575.129 us; speedup 1.0000x reference)
//
#include <hip/hip_runtime.h>
#include <hip/hip_bf16.h>
#include <math.h>

#define NH   32
#define NKV  8
#define HDIM 128
#define BATCH 2
#define SEQ  1024
#define KSUB 256
#define DSUB 16
#define PQM  8

// ---------------------------------------------------------------------------
// GEMM: C[M x N] = A[M x K] @ W[N x K]^T + bias (bias may be null)
// 128x128 tile, BK=16, 256 threads, 8x8 microtile per thread. fp32.
// ---------------------------------------------------------------------------
__global__ __launch_bounds__(256) void gemm_bias(
    const float* __restrict__ A, const float* __restrict__ W,
    const float* __restrict__ bias, float* __restrict__ C,
    int Mrows, int N, int K)
{
    __shared__ float As[16][132];
    __shared__ float Bs[16][132];
    const int tid  = threadIdx.x;
    const int row0 = blockIdx.y * 128, col0 = blockIdx.x * 128;
    const int lr = tid >> 1;            // 0..127 row within tile
    const int lk = (tid & 1) * 8;       // 0 or 8 within BK
    const int ty = tid >> 4, tx = tid & 15;

    float acc[8][8];
    #pragma unroll
    for (int i = 0; i < 8; i++)
        #pragma unroll
        for (int j = 0; j < 8; j++) acc[i][j] = 0.f;

    const float* Ap = A + (size_t)(row0 + lr) * K + lk;
    const float* Wp = W + (size_t)(col0 + lr) * K + lk;

    for (int k0 = 0; k0 < K; k0 += 16) {
        float4 a0 = *(const float4*)(Ap + k0);
        float4 a1 = *(const float4*)(Ap + k0 + 4);
        float4 b0 = *(const float4*)(Wp + k0);
        float4 b1 = *(const float4*)(Wp + k0 + 4);
        __syncthreads();
        As[lk+0][lr]=a0.x; As[lk+1][lr]=a0.y; As[lk+2][lr]=a0.z; As[lk+3][lr]=a0.w;
        As[lk+4][lr]=a1.x; As[lk+5][lr]=a1.y; As[lk+6][lr]=a1.z; As[lk+7][lr]=a1.w;
        Bs[lk+0][lr]=b0.x; Bs[lk+1][lr]=b0.y; Bs[lk+2][lr]=b0.z; Bs[lk+3][lr]=b0.w;
        Bs[lk+4][lr]=b1.x; Bs[lk+5][lr]=b1.y; Bs[lk+6][lr]=b1.z; Bs[lk+7][lr]=b1.w;
        __syncthreads();
        #pragma unroll
        for (int kk = 0; kk < 16; kk++) {
            float av[8], bv[8];
            *(float4*)&av[0] = *(const float4*)&As[kk][ty*8];
            *(float4*)&av[4] = *(const float4*)&As[kk][ty*8+4];
            *(float4*)&bv[0] = *(const float4*)&Bs[kk][tx*8];
            *(float4*)&bv[4] = *(const float4*)&Bs[kk][tx*8+4];
            #pragma unroll
            for (int i = 0; i < 8; i++)
                #pragma unroll
                for (int j = 0; j < 8; j++)
                    acc[i][j] += av[i] * bv[j];
        }
    }

    #pragma unroll
    for (int i = 0; i < 8; i++) {
        int r = row0 + ty*8 + i;
        #pragma unroll
        for (int j = 0; j < 8; j += 4) {
            int c = col0 + tx*8 + j;
            float4 v;
            v.x = acc[i][j+0] + (bias ? bias[c+0] : 0.f);
            v.y = acc[i][j+1] + (bias ? bias[c+1] : 0.f);
            v.z = acc[i][j+2] + (bias ? bias[c+2] : 0.f);
            v.w = acc[i][j+3] + (bias ? bias[c+3] : 0.f);
            *(float4*)&C[(size_t)r * N + c] = v;
        }
    }
}

// ---------------------------------------------------------------------------
// RoPE cos/sin table: [SEQ][64] each. inv_freq from double pow rounded to
// fp32, freq as fp32 multiply (matching the reference's fp32 chain), then
// double-precision trig of the fp32 argument.
// ---------------------------------------------------------------------------
__global__ void rope_table(float* __restrict__ cosT, float* __restrict__ sinT)
{
    int idx = blockIdx.x * 256 + threadIdx.x;   // 65536 = 1024*64
    int s = idx >> 6, i = idx & 63;
    float inv_f = (float)pow(1.0e6, -(double)i / 64.0);
    float freq  = (float)s * inv_f;             // fp32 multiply like reference
    cosT[idx] = (float)cos((double)freq);
    sinT[idx] = (float)sin((double)freq);
}

// X: [BATCH*SEQ][nh*HDIM] in-place rotate-half RoPE.
__global__ void rope_apply(float* __restrict__ X,
                           const float* __restrict__ cosT,
                           const float* __restrict__ sinT, int nh)
{
    int idx = blockIdx.x * 256 + threadIdx.x;   // (row*nh + h)*64 + i
    int i = idx & 63;
    int t = idx >> 6;
    int h = t % nh;
    int row = t / nh;
    int s = row & (SEQ - 1);
    float c  = cosT[s*64 + i];
    float sv = sinT[s*64 + i];
    float* p = X + (size_t)row * (nh * HDIM) + h * HDIM;
    float x1 = p[i], x2 = p[i + 64];
    p[i]      = x1 * c - x2 * sv;
    p[i + 64] = x2 * c + x1 * sv;
}

// ---------------------------------------------------------------------------
// PQ round-trip for one subspace m per block-row.
// X: [BATCH*SEQ][NKV*HDIM] fp32; cent: [PQM][KSUB][DSUB]; rec: bf16 same
// layout as X. grid = (64, PQM), 256 threads; each thread owns one (b,h,s).
// ---------------------------------------------------------------------------
__global__ __launch_bounds__(256) void pq_kernel(
    const float* __restrict__ X, const float* __restrict__ cent,
    __hip_bfloat16* __restrict__ rec)
{
    __shared__ float Cs[KSUB * DSUB];   // 16 KB
    __shared__ float CC[KSUB];
    const int m = blockIdx.y;
    const float* cm = cent + (size_t)m * KSUB * DSUB;
    for (int t = threadIdx.x; t < KSUB * DSUB; t += 256) Cs[t] = cm[t];
    __syncthreads();
    {
        int k = threadIdx.x;            // 256 threads = KSUB
        float s = 0.f;
        #pragma unroll
        for (int d = 0; d < DSUB; d++) s += Cs[k*DSUB + d] * Cs[k*DSUB + d];
        CC[k] = s;
    }
    __syncthreads();

    int p  = blockIdx.x * 256 + threadIdx.x;    // 0 .. 16383
    int s_ = p & (SEQ - 1);
    int bh = p >> 10;                            // b*NKV + h
    int b  = bh >> 3, h = bh & 7;
    const float* x = X + (size_t)(b*SEQ + s_) * (NKV*HDIM) + h*HDIM + m*DSUB;

    float xv[DSUB], xx = 0.f;
    #pragma unroll
    for (int d = 0; d < DSUB; d++) { xv[d] = x[d]; xx += xv[d]*xv[d]; }

    float best = INFINITY; int bk = 0;
    for (int k = 0; k < KSUB; k++) {
        float dot = 0.f;
        #pragma unroll
        for (int d = 0; d < DSUB; d++) dot += xv[d] * Cs[k*DSUB + d];
        float d2 = xx + CC[k] - 2.f * dot;
        if (d2 < best) { best = d2; bk = k; }   // first-min tie-break (argmin)
    }

    __hip_bfloat16* r = rec + (size_t)(b*SEQ + s_) * (NKV*HDIM) + h*HDIM + m*DSUB;
    #pragma unroll
    for (int d = 0; d < DSUB; d++) r[d] = __float2bfloat16(Cs[bk*DSUB + d]);
}

// ---------------------------------------------------------------------------
// Attention: one wave per (b, h, q) row. Online softmax, fp32 accum, bf16 K/V.
// Lane l owns dims l and l+64. Q pre-scaled by 1/sqrt(128).
// ---------------------------------------------------------------------------
__global__ __launch_bounds__(256) void attn_kernel(
    const float* __restrict__ Q, const __hip_bfloat16* __restrict__ K,
    const __hip_bfloat16* __restrict__ V, float* __restrict__ O)
{
    int wave = blockIdx.x * 4 + (threadIdx.x >> 6);
    int lane = threadIdx.x & 63;
    int q  = wave & (SEQ - 1);
    int bh = wave >> 10;
    int h  = bh & (NH - 1);
    int b  = bh >> 5;

    const float scale = 0.08838834764831845f;   // 1/sqrt(128)
    const float* qp = Q + (size_t)(b*SEQ + q) * (NH*HDIM) + h*HDIM;
    float q0 = qp[lane] * scale;
    float q1 = qp[lane + 64] * scale;

    int kvh = h >> 2;
    const __hip_bfloat16* Kb = K + (size_t)(b*SEQ) * (NKV*HDIM) + kvh*HDIM;
    const __hip_bfloat16* Vb = V + (size_t)(b*SEQ) * (NKV*HDIM) + kvh*HDIM;

    float m = -INFINITY, l = 0.f, a0 = 0.f, a1 = 0.f;
    for (int j = 0; j <= q; j++) {
        const __hip_bfloat16* kr = Kb + (size_t)j * (NKV*HDIM);
        float k0 = __bfloat162float(kr[lane]);
        float k1 = __bfloat162float(kr[lane + 64]);
        float s = q0*k0 + q1*k1;
        #pragma unroll
        for (int off = 1; off < 64; off <<= 1) s += __shfl_xor(s, off, 64);

        float mn = fmaxf(m, s);
        float pv = expf(s - mn);
        float cf = expf(m - mn);   // exp(-inf)=0 on first iter
        const __hip_bfloat16* vr = Vb + (size_t)j * (NKV*HDIM);
        float v0 = __bfloat162float(vr[lane]);
        float v1 = __bfloat162float(vr[lane + 64]);
        l  = l * cf + pv;
        a0 = a0 * cf + pv * v0;
        a1 = a1 * cf + pv * v1;
        m = mn;
    }

    float* op = O + (size_t)(b*SEQ + q) * (NH*HDIM) + h*HDIM;
    op[lane]      = a0 / l;
    op[lane + 64] = a1 / l;
}

// ---------------------------------------------------------------------------
extern "C" void kernel_launch(void* const* d_in, const int* in_sizes, int n_in,
                              void* d_out, int out_size, void* d_ws, size_t ws_size,
                              hipStream_t stream)
{
    const float* hs  = (const float*)d_in[0];
    const float* q_w = (const float*)d_in[1];
    const float* q_b = (const float*)d_in[2];
    const float* k_w = (const float*)d_in[3];
    const float* k_b = (const float*)d_in[4];
    const float* v_w = (const float*)d_in[5];
    const float* v_b = (const float*)d_in[6];
    const float* o_w = (const float*)d_in[7];
    const float* k_c = (const float*)d_in[8];
    const float* v_c = (const float*)d_in[9];
    float* out = (float*)d_out;

    char* ws = (char*)d_ws;
    float*          Qf      = (float*)(ws);                         // 33,554,432 B
    float*          Kf      = (float*)(ws + 33554432);              //  8,388,608 B
    float*          Vf      = (float*)(ws + 41943040);              //  8,388,608 B
    float*          AttnOut = (float*)(ws + 50331648);              // 33,554,432 B
    __hip_bfloat16* Krec    = (__hip_bfloat16*)(ws + 83886080);     //  4,194,304 B
    __hip_bfloat16* Vrec    = (__hip_bfloat16*)(ws + 88080384);     //  4,194,304 B
    float*          cosT    = (float*)(ws + 92274688);              //    262,144 B
    float*          sinT    = (float*)(ws + 92536832);              //    262,144 B

    const int Mrows = BATCH * SEQ;      // 2048

    rope_table<<<dim3(256), dim3(256), 0, stream>>>(cosT, sinT);

    gemm_bias<<<dim3(32, 16), 256, 0, stream>>>(hs, q_w, q_b, Qf, Mrows, NH*HDIM,  4096);
    gemm_bias<<<dim3(8,  16), 256, 0, stream>>>(hs, k_w, k_b, Kf, Mrows, NKV*HDIM, 4096);
    gemm_bias<<<dim3(8,  16), 256, 0, stream>>>(hs, v_w, v_b, Vf, Mrows, NKV*HDIM, 4096);

    rope_apply<<<dim3(16384), 256, 0, stream>>>(Qf, cosT, sinT, NH);
    rope_apply<<<dim3(4096),  256, 0, stream>>>(Kf, cosT, sinT, NKV);

    pq_kernel<<<dim3(64, PQM), 256, 0, stream>>>(Kf, k_c, Krec);
    pq_kernel<<<dim3(64, PQM), 256, 0, stream>>>(Vf, v_c, Vrec);

    attn_kernel<<<dim3(16384), 256, 0, stream>>>(Qf, Krec, Vrec, AttnOut);

    gemm_bias<<<dim3(32, 16), 256, 0, stream>>>(AttnOut, o_w, nullptr, out, Mrows, NH*HDIM, 4096);
}

// Round 2
// 2872.205 us; speedup vs baseline: 1.9411x; 1.9411x over previous
//
#include <hip/hip_runtime.h>
#include <hip/hip_bf16.h>
#include <math.h>

#define NH   32
#define NKV  8
#define HDIM 128
#define BATCH 2
#define SEQ  1024
#define KSUB 256
#define DSUB 16
#define PQM  8

typedef __attribute__((ext_vector_type(8))) short bf16x8;
typedef __attribute__((ext_vector_type(4))) float f32x4;

__device__ inline short f2bf(float x) {
    unsigned u = __builtin_bit_cast(unsigned, x);
    unsigned r = (u + 0x7fff + ((u >> 16) & 1)) >> 16;
    return (short)r;
}

// ---------------------------------------------------------------------------
// GEMM: C[M x N] = A[M x K] @ W[N x K]^T + bias (bias may be null). fp32.
// ---------------------------------------------------------------------------
__global__ __launch_bounds__(256) void gemm_bias(
    const float* __restrict__ A, const float* __restrict__ W,
    const float* __restrict__ bias, float* __restrict__ C,
    int Mrows, int N, int K)
{
    __shared__ float As[16][132];
    __shared__ float Bs[16][132];
    const int tid  = threadIdx.x;
    const int row0 = blockIdx.y * 128, col0 = blockIdx.x * 128;
    const int lr = tid >> 1;
    const int lk = (tid & 1) * 8;
    const int ty = tid >> 4, tx = tid & 15;

    float acc[8][8];
    #pragma unroll
    for (int i = 0; i < 8; i++)
        #pragma unroll
        for (int j = 0; j < 8; j++) acc[i][j] = 0.f;

    const float* Ap = A + (size_t)(row0 + lr) * K + lk;
    const float* Wp = W + (size_t)(col0 + lr) * K + lk;

    for (int k0 = 0; k0 < K; k0 += 16) {
        float4 a0 = *(const float4*)(Ap + k0);
        float4 a1 = *(const float4*)(Ap + k0 + 4);
        float4 b0 = *(const float4*)(Wp + k0);
        float4 b1 = *(const float4*)(Wp + k0 + 4);
        __syncthreads();
        As[lk+0][lr]=a0.x; As[lk+1][lr]=a0.y; As[lk+2][lr]=a0.z; As[lk+3][lr]=a0.w;
        As[lk+4][lr]=a1.x; As[lk+5][lr]=a1.y; As[lk+6][lr]=a1.z; As[lk+7][lr]=a1.w;
        Bs[lk+0][lr]=b0.x; Bs[lk+1][lr]=b0.y; Bs[lk+2][lr]=b0.z; Bs[lk+3][lr]=b0.w;
        Bs[lk+4][lr]=b1.x; Bs[lk+5][lr]=b1.y; Bs[lk+6][lr]=b1.z; Bs[lk+7][lr]=b1.w;
        __syncthreads();
        #pragma unroll
        for (int kk = 0; kk < 16; kk++) {
            float av[8], bv[8];
            *(float4*)&av[0] = *(const float4*)&As[kk][ty*8];
            *(float4*)&av[4] = *(const float4*)&As[kk][ty*8+4];
            *(float4*)&bv[0] = *(const float4*)&Bs[kk][tx*8];
            *(float4*)&bv[4] = *(const float4*)&Bs[kk][tx*8+4];
            #pragma unroll
            for (int i = 0; i < 8; i++)
                #pragma unroll
                for (int j = 0; j < 8; j++)
                    acc[i][j] += av[i] * bv[j];
        }
    }

    #pragma unroll
    for (int i = 0; i < 8; i++) {
        int r = row0 + ty*8 + i;
        #pragma unroll
        for (int j = 0; j < 8; j += 4) {
            int c = col0 + tx*8 + j;
            float4 v;
            v.x = acc[i][j+0] + (bias ? bias[c+0] : 0.f);
            v.y = acc[i][j+1] + (bias ? bias[c+1] : 0.f);
            v.z = acc[i][j+2] + (bias ? bias[c+2] : 0.f);
            v.w = acc[i][j+3] + (bias ? bias[c+3] : 0.f);
            *(float4*)&C[(size_t)r * N + c] = v;
        }
    }
}

// ---------------------------------------------------------------------------
__global__ void rope_table(float* __restrict__ cosT, float* __restrict__ sinT)
{
    int idx = blockIdx.x * 256 + threadIdx.x;
    int s = idx >> 6, i = idx & 63;
    float inv_f = (float)pow(1.0e6, -(double)i / 64.0);
    float freq  = (float)s * inv_f;
    cosT[idx] = (float)cos((double)freq);
    sinT[idx] = (float)sin((double)freq);
}

// K: in-place fp32 RoPE.
__global__ void rope_apply(float* __restrict__ X,
                           const float* __restrict__ cosT,
                           const float* __restrict__ sinT, int nh)
{
    int idx = blockIdx.x * 256 + threadIdx.x;
    int i = idx & 63;
    int t = idx >> 6;
    int h = t % nh;
    int row = t / nh;
    int s = row & (SEQ - 1);
    float c  = cosT[s*64 + i];
    float sv = sinT[s*64 + i];
    float* p = X + (size_t)row * (nh * HDIM) + h * HDIM;
    float x1 = p[i], x2 = p[i + 64];
    p[i]      = x1 * c - x2 * sv;
    p[i + 64] = x2 * c + x1 * sv;
}

// Q: RoPE + fold softmax scale, emit bf16.
__global__ void rope_apply_q(const float* __restrict__ Qf,
                             __hip_bfloat16* __restrict__ Qbf,
                             const float* __restrict__ cosT,
                             const float* __restrict__ sinT)
{
    int idx = blockIdx.x * 256 + threadIdx.x;   // (row*32 + h)*64 + i
    int i = idx & 63;
    int t = idx >> 6;
    int h = t & 31;
    int row = t >> 5;
    int s = row & (SEQ - 1);
    const float scale = 0.08838834764831845f;   // 1/sqrt(128)
    float c  = cosT[s*64 + i];
    float sv = sinT[s*64 + i];
    const float* p = Qf + (size_t)row * 4096 + h * HDIM;
    float x1 = p[i], x2 = p[i + 64];
    __hip_bfloat16* q = Qbf + (size_t)row * 4096 + h * HDIM;
    q[i]      = __float2bfloat16((x1 * c - x2 * sv) * scale);
    q[i + 64] = __float2bfloat16((x2 * c + x1 * sv) * scale);
}

// ---------------------------------------------------------------------------
// PQ round-trip (unchanged, fp32-exact distances).
// ---------------------------------------------------------------------------
__global__ __launch_bounds__(256) void pq_kernel(
    const float* __restrict__ X, const float* __restrict__ cent,
    __hip_bfloat16* __restrict__ rec)
{
    __shared__ float Cs[KSUB * DSUB];
    __shared__ float CC[KSUB];
    const int m = blockIdx.y;
    const float* cm = cent + (size_t)m * KSUB * DSUB;
    for (int t = threadIdx.x; t < KSUB * DSUB; t += 256) Cs[t] = cm[t];
    __syncthreads();
    {
        int k = threadIdx.x;
        float s = 0.f;
        #pragma unroll
        for (int d = 0; d < DSUB; d++) s += Cs[k*DSUB + d] * Cs[k*DSUB + d];
        CC[k] = s;
    }
    __syncthreads();

    int p  = blockIdx.x * 256 + threadIdx.x;
    int s_ = p & (SEQ - 1);
    int bh = p >> 10;
    int b  = bh >> 3, h = bh & 7;
    const float* x = X + (size_t)(b*SEQ + s_) * (NKV*HDIM) + h*HDIM + m*DSUB;

    float xv[DSUB], xx = 0.f;
    #pragma unroll
    for (int d = 0; d < DSUB; d++) { xv[d] = x[d]; xx += xv[d]*xv[d]; }

    float best = INFINITY; int bk = 0;
    for (int k = 0; k < KSUB; k++) {
        float dot = 0.f;
        #pragma unroll
        for (int d = 0; d < DSUB; d++) dot += xv[d] * Cs[k*DSUB + d];
        float d2 = xx + CC[k] - 2.f * dot;
        if (d2 < best) { best = d2; bk = k; }
    }

    __hip_bfloat16* r = rec + (size_t)(b*SEQ + s_) * (NKV*HDIM) + h*HDIM + m*DSUB;
    #pragma unroll
    for (int d = 0; d < DSUB; d++) r[d] = __float2bfloat16(Cs[bk*DSUB + d]);
}

// ---------------------------------------------------------------------------
// MFMA flash attention. Block = 4 waves x 16 Q rows (64-row tile) per (b,h).
// KV tiles of 32 keys: K XOR-swizzled in LDS, V transposed [d][j] (+pad).
// mfma_f32_16x16x32_bf16; C/D layout col=lane&15, row=(lane>>4)*4+reg.
// ---------------------------------------------------------------------------
__global__ __launch_bounds__(256) void attn_mfma(
    const short* __restrict__ Qbf, const short* __restrict__ K,
    const short* __restrict__ V, float* __restrict__ O)
{
    __shared__ short Ks[32 * 128];      // swizzled: idx = j*128 + (d ^ ((j&7)<<3))
    __shared__ short Vt[128 * 40];      // Vt[d*40 + j]
    __shared__ short Ps[4 * 16 * 40];   // per-wave P tile [q][j], stride 40

    const int tid  = threadIdx.x;
    const int wid  = tid >> 6, lane = tid & 63;
    const int l15  = lane & 15, l4 = lane >> 4;
    const int qt   = gridDim.x - 1 - blockIdx.x;   // heaviest blocks first
    const int qb   = qt * 64;
    const int h    = blockIdx.y & 31, b = blockIdx.y >> 5;
    const int kvh  = h >> 2;
    const int qw   = qb + wid * 16;

    // Q fragments: A[row=l15][k=l4*8+j], 4 k-steps of 32
    bf16x8 qf[4];
    {
        const short* qp = Qbf + (size_t)(b*SEQ + qw + l15) * 4096 + h*HDIM + l4*8;
        #pragma unroll
        for (int ks = 0; ks < 4; ks++) qf[ks] = *(const bf16x8*)(qp + 32*ks);
    }

    f32x4 o[8];
    #pragma unroll
    for (int i = 0; i < 8; i++) o[i] = (f32x4)0.f;
    float m[4]  = {-1e30f, -1e30f, -1e30f, -1e30f};
    float ls[4] = {0.f, 0.f, 0.f, 0.f};

    const int ntiles = 2 * (qt + 1);
    const short* Kg = K + (size_t)b * SEQ * 1024 + kvh * HDIM;
    const short* Vg = V + (size_t)b * SEQ * 1024 + kvh * HDIM;

    for (int t = 0; t < ntiles; t++) {
        const int jbase = t * 32;
        __syncthreads();
        {   // stage K tile (32 keys x 128 d), XOR-swizzled rows
            int j = tid >> 3, d0 = (tid & 7) * 16;
            const short* src = Kg + (size_t)(jbase + j) * 1024 + d0;
            bf16x8 a = *(const bf16x8*)src;
            bf16x8 c = *(const bf16x8*)(src + 8);
            int sw = (j & 7) << 3;
            *(bf16x8*)(Ks + j*128 + (d0 ^ sw))       = a;
            *(bf16x8*)(Ks + j*128 + ((d0 + 8) ^ sw)) = c;
        }
        {   // stage V tile transposed: Vt[d][j]
            int j = tid & 31, e0 = (tid >> 5) * 16;
            const short* src = Vg + (size_t)(jbase + j) * 1024 + e0;
            bf16x8 a = *(const bf16x8*)src;
            bf16x8 c = *(const bf16x8*)(src + 8);
            #pragma unroll
            for (int i = 0; i < 8; i++) {
                Vt[(e0 + i)     * 40 + j] = a[i];
                Vt[(e0 + i + 8) * 40 + j] = c[i];
            }
        }
        __syncthreads();

        if (jbase >= qw + 16) continue;   // fully masked for this wave

        // ---- QK^T: S[16q][32j] as two 16-col fragments
        f32x4 sc0 = (f32x4)0.f, sc1 = (f32x4)0.f;
        #pragma unroll
        for (int ks = 0; ks < 4; ks++) {
            int d0 = 32*ks + l4*8;
            int j0 = l15, j1 = l15 + 16;
            bf16x8 kb0 = *(const bf16x8*)(Ks + j0*128 + (d0 ^ ((j0 & 7) << 3)));
            bf16x8 kb1 = *(const bf16x8*)(Ks + j1*128 + (d0 ^ ((j1 & 7) << 3)));
            sc0 = __builtin_amdgcn_mfma_f32_16x16x32_bf16(qf[ks], kb0, sc0, 0, 0, 0);
            sc1 = __builtin_amdgcn_mfma_f32_16x16x32_bf16(qf[ks], kb1, sc1, 0, 0, 0);
        }

        // ---- causal mask + block max
        float mx[4];
        #pragma unroll
        for (int r = 0; r < 4; r++) {
            int q_r = qw + l4*4 + r;
            if (jbase + l15      > q_r) sc0[r] = -1e30f;
            if (jbase + 16 + l15 > q_r) sc1[r] = -1e30f;
            mx[r] = fmaxf(sc0[r], sc1[r]);
        }
        #pragma unroll
        for (int off = 1; off < 16; off <<= 1)
            #pragma unroll
            for (int r = 0; r < 4; r++)
                mx[r] = fmaxf(mx[r], __shfl_xor(mx[r], off, 64));

        // ---- online softmax update; P -> per-wave LDS (bf16)
        #pragma unroll
        for (int r = 0; r < 4; r++) {
            float mn = fmaxf(m[r], mx[r]);
            float cf = __expf(m[r] - mn);
            m[r] = mn;
            float p0 = __expf(sc0[r] - mn);
            float p1 = __expf(sc1[r] - mn);
            ls[r] = ls[r] * cf + p0 + p1;
            #pragma unroll
            for (int dt = 0; dt < 8; dt++) o[dt][r] *= cf;
            Ps[wid*640 + (l4*4 + r)*40 + l15]      = f2bf(p0);
            Ps[wid*640 + (l4*4 + r)*40 + l15 + 16] = f2bf(p1);
        }

        // ---- PV: O[16q][128d] += P[16x32] . V[32x128]
        bf16x8 pa = *(const bf16x8*)(Ps + wid*640 + l15*40 + l4*8);
        #pragma unroll
        for (int dt = 0; dt < 8; dt++) {
            bf16x8 vb = *(const bf16x8*)(Vt + (16*dt + l15)*40 + l4*8);
            o[dt] = __builtin_amdgcn_mfma_f32_16x16x32_bf16(pa, vb, o[dt], 0, 0, 0);
        }
    }

    // ---- denominator reduce + store
    #pragma unroll
    for (int off = 1; off < 16; off <<= 1)
        #pragma unroll
        for (int r = 0; r < 4; r++)
            ls[r] += __shfl_xor(ls[r], off, 64);

    float* Op = O + (size_t)(b*SEQ + qw + l4*4) * 4096 + h*HDIM + l15;
    #pragma unroll
    for (int r = 0; r < 4; r++) {
        float inv = 1.f / ls[r];
        #pragma unroll
        for (int dt = 0; dt < 8; dt++)
            Op[(size_t)r * 4096 + dt * 16] = o[dt][r] * inv;
    }
}

// ---------------------------------------------------------------------------
extern "C" void kernel_launch(void* const* d_in, const int* in_sizes, int n_in,
                              void* d_out, int out_size, void* d_ws, size_t ws_size,
                              hipStream_t stream)
{
    const float* hs  = (const float*)d_in[0];
    const float* q_w = (const float*)d_in[1];
    const float* q_b = (const float*)d_in[2];
    const float* k_w = (const float*)d_in[3];
    const float* k_b = (const float*)d_in[4];
    const float* v_w = (const float*)d_in[5];
    const float* v_b = (const float*)d_in[6];
    const float* o_w = (const float*)d_in[7];
    const float* k_c = (const float*)d_in[8];
    const float* v_c = (const float*)d_in[9];
    float* out = (float*)d_out;

    char* ws = (char*)d_ws;
    float*          Qf      = (float*)(ws);                         // 32 MB
    float*          Kf      = (float*)(ws + 33554432);              //  8 MB
    float*          Vf      = (float*)(ws + 41943040);              //  8 MB
    float*          AttnOut = (float*)(ws + 50331648);              // 32 MB
    __hip_bfloat16* Krec    = (__hip_bfloat16*)(ws + 83886080);     //  4 MB
    __hip_bfloat16* Vrec    = (__hip_bfloat16*)(ws + 88080384);     //  4 MB
    float*          cosT    = (float*)(ws + 92274688);
    float*          sinT    = (float*)(ws + 92536832);
    // Qbf overlays Kf+Vf (16 MB) — both dead once the PQ kernels have run.
    __hip_bfloat16* Qbf     = (__hip_bfloat16*)(ws + 33554432);

    const int Mrows = BATCH * SEQ;      // 2048

    rope_table<<<dim3(256), dim3(256), 0, stream>>>(cosT, sinT);

    gemm_bias<<<dim3(32, 16), 256, 0, stream>>>(hs, q_w, q_b, Qf, Mrows, NH*HDIM,  4096);
    gemm_bias<<<dim3(8,  16), 256, 0, stream>>>(hs, k_w, k_b, Kf, Mrows, NKV*HDIM, 4096);
    gemm_bias<<<dim3(8,  16), 256, 0, stream>>>(hs, v_w, v_b, Vf, Mrows, NKV*HDIM, 4096);

    rope_apply<<<dim3(4096), 256, 0, stream>>>(Kf, cosT, sinT, NKV);

    pq_kernel<<<dim3(64, PQM), 256, 0, stream>>>(Kf, k_c, Krec);
    pq_kernel<<<dim3(64, PQM), 256, 0, stream>>>(Vf, v_c, Vrec);

    // Now Kf/Vf are dead: produce bf16 RoPE'd+scaled Q over their storage.
    rope_apply_q<<<dim3(16384), 256, 0, stream>>>(Qf, Qbf, cosT, sinT);

    attn_mfma<<<dim3(16, 64), 256, 0, stream>>>((const short*)Qbf, (const short*)Krec,
                                                (const short*)Vrec, AttnOut);

    gemm_bias<<<dim3(32, 16), 256, 0, stream>>>(AttnOut, o_w, nullptr, out, Mrows, NH*HDIM, 4096);
}

// Round 3
// 1456.826 us; speedup vs baseline: 3.8269x; 1.9716x over previous
//
#include <hip/hip_runtime.h>
#include <hip/hip_bf16.h>
#include <math.h>

#define NH   32
#define NKV  8
#define HDIM 128
#define BATCH 2
#define SEQ  1024
#define KSUB 256
#define DSUB 16
#define PQM  8

typedef __attribute__((ext_vector_type(8))) short bf16x8;
typedef __attribute__((ext_vector_type(4))) float f32x4;

__device__ inline short f2bf(float x) {
    unsigned u = __builtin_bit_cast(unsigned, x);
    unsigned r = (u + 0x7fff + ((u >> 16) & 1)) >> 16;
    return (short)r;
}

__device__ inline void gload_lds16(const void* g, void* l) {
    __builtin_amdgcn_global_load_lds(
        (const __attribute__((address_space(1))) unsigned*)g,
        (__attribute__((address_space(3))) unsigned*)l, 16, 0, 0);
}

// ---------------------------------------------------------------------------
// fp32 GEMM (K/V projections only — feeds PQ argmin, must stay fp32).
// ---------------------------------------------------------------------------
__global__ __launch_bounds__(256) void gemm_bias(
    const float* __restrict__ A, const float* __restrict__ W,
    const float* __restrict__ bias, float* __restrict__ C,
    int Mrows, int N, int K)
{
    __shared__ float As[16][132];
    __shared__ float Bs[16][132];
    const int tid  = threadIdx.x;
    const int row0 = blockIdx.y * 128, col0 = blockIdx.x * 128;
    const int lr = tid >> 1;
    const int lk = (tid & 1) * 8;
    const int ty = tid >> 4, tx = tid & 15;

    float acc[8][8];
    #pragma unroll
    for (int i = 0; i < 8; i++)
        #pragma unroll
        for (int j = 0; j < 8; j++) acc[i][j] = 0.f;

    const float* Ap = A + (size_t)(row0 + lr) * K + lk;
    const float* Wp = W + (size_t)(col0 + lr) * K + lk;

    for (int k0 = 0; k0 < K; k0 += 16) {
        float4 a0 = *(const float4*)(Ap + k0);
        float4 a1 = *(const float4*)(Ap + k0 + 4);
        float4 b0 = *(const float4*)(Wp + k0);
        float4 b1 = *(const float4*)(Wp + k0 + 4);
        __syncthreads();
        As[lk+0][lr]=a0.x; As[lk+1][lr]=a0.y; As[lk+2][lr]=a0.z; As[lk+3][lr]=a0.w;
        As[lk+4][lr]=a1.x; As[lk+5][lr]=a1.y; As[lk+6][lr]=a1.z; As[lk+7][lr]=a1.w;
        Bs[lk+0][lr]=b0.x; Bs[lk+1][lr]=b0.y; Bs[lk+2][lr]=b0.z; Bs[lk+3][lr]=b0.w;
        Bs[lk+4][lr]=b1.x; Bs[lk+5][lr]=b1.y; Bs[lk+6][lr]=b1.z; Bs[lk+7][lr]=b1.w;
        __syncthreads();
        #pragma unroll
        for (int kk = 0; kk < 16; kk++) {
            float av[8], bv[8];
            *(float4*)&av[0] = *(const float4*)&As[kk][ty*8];
            *(float4*)&av[4] = *(const float4*)&As[kk][ty*8+4];
            *(float4*)&bv[0] = *(const float4*)&Bs[kk][tx*8];
            *(float4*)&bv[4] = *(const float4*)&Bs[kk][tx*8+4];
            #pragma unroll
            for (int i = 0; i < 8; i++)
                #pragma unroll
                for (int j = 0; j < 8; j++)
                    acc[i][j] += av[i] * bv[j];
        }
    }

    #pragma unroll
    for (int i = 0; i < 8; i++) {
        int r = row0 + ty*8 + i;
        #pragma unroll
        for (int j = 0; j < 8; j += 4) {
            int c = col0 + tx*8 + j;
            float4 v;
            v.x = acc[i][j+0] + (bias ? bias[c+0] : 0.f);
            v.y = acc[i][j+1] + (bias ? bias[c+1] : 0.f);
            v.z = acc[i][j+2] + (bias ? bias[c+2] : 0.f);
            v.w = acc[i][j+3] + (bias ? bias[c+3] : 0.f);
            *(float4*)&C[(size_t)r * N + c] = v;
        }
    }
}

// ---------------------------------------------------------------------------
// bf16 MFMA GEMM: C[M x N] = A[M x K] @ W[N x K]^T + bias. fp32 out.
// 128x128 tile, BK=32, 4 waves; global_load_lds(16B) into linear LDS;
// fragment ds_read_b128 tiles a contiguous 1KB/wave block -> conflict-free.
// ---------------------------------------------------------------------------
__global__ __launch_bounds__(256) void gemm_mfma_bf16(
    const short* __restrict__ A, const short* __restrict__ W,
    const float* __restrict__ bias, float* __restrict__ C,
    int N, int K)
{
    __shared__ short Al[128 * 32];
    __shared__ short Bl[128 * 32];

    const int tid = threadIdx.x;
    const int wid = tid >> 6, lane = tid & 63;
    const int l15 = lane & 15, l4 = lane >> 4;
    const int row0 = blockIdx.y * 128, col0 = blockIdx.x * 128;
    const int wr = (wid >> 1) * 64, wc = (wid & 1) * 64;

    f32x4 acc[4][4];
    #pragma unroll
    for (int m = 0; m < 4; m++)
        #pragma unroll
        for (int n = 0; n < 4; n++) acc[m][n] = (f32x4)0.f;

    // staging: chunk ci in [0,512): row = ci>>2, k = (ci&3)*8, lds off = ci*16B
    const int ci0 = tid, ci1 = tid + 256;
    const short* Ag0 = A + (size_t)(row0 + (ci0 >> 2)) * K + (ci0 & 3) * 8;
    const short* Ag1 = A + (size_t)(row0 + (ci1 >> 2)) * K + (ci1 & 3) * 8;
    const short* Wg0 = W + (size_t)(col0 + (ci0 >> 2)) * K + (ci0 & 3) * 8;
    const short* Wg1 = W + (size_t)(col0 + (ci1 >> 2)) * K + (ci1 & 3) * 8;

    for (int k0 = 0; k0 < K; k0 += 32) {
        __syncthreads();
        gload_lds16(Ag0 + k0, Al + ci0 * 8);
        gload_lds16(Ag1 + k0, Al + ci1 * 8);
        gload_lds16(Wg0 + k0, Bl + ci0 * 8);
        gload_lds16(Wg1 + k0, Bl + ci1 * 8);
        __syncthreads();

        bf16x8 af[4], bfr[4];
        #pragma unroll
        for (int m = 0; m < 4; m++)
            af[m] = *(const bf16x8*)(Al + (wr + m*16 + l15) * 32 + l4 * 8);
        #pragma unroll
        for (int n = 0; n < 4; n++)
            bfr[n] = *(const bf16x8*)(Bl + (wc + n*16 + l15) * 32 + l4 * 8);
        #pragma unroll
        for (int m = 0; m < 4; m++)
            #pragma unroll
            for (int n = 0; n < 4; n++)
                acc[m][n] = __builtin_amdgcn_mfma_f32_16x16x32_bf16(af[m], bfr[n], acc[m][n], 0, 0, 0);
    }

    float bv[4];
    #pragma unroll
    for (int n = 0; n < 4; n++)
        bv[n] = bias ? bias[col0 + wc + n*16 + l15] : 0.f;

    #pragma unroll
    for (int m = 0; m < 4; m++) {
        #pragma unroll
        for (int r = 0; r < 4; r++) {
            float* Cp = C + (size_t)(row0 + wr + m*16 + l4*4 + r) * N + col0 + wc + l15;
            #pragma unroll
            for (int n = 0; n < 4; n++)
                Cp[n * 16] = acc[m][n][r] + bv[n];
        }
    }
}

// ---------------------------------------------------------------------------
// fp32 -> bf16 cast, vectorized (n4 = n/4 float4 chunks).
// ---------------------------------------------------------------------------
__global__ void cast_bf16(const float* __restrict__ x, ushort* __restrict__ y, int n4)
{
    int i = blockIdx.x * 256 + threadIdx.x;
    if (i < n4) {
        float4 v = ((const float4*)x)[i];
        ushort4 o;
        o.x = (ushort)f2bf(v.x); o.y = (ushort)f2bf(v.y);
        o.z = (ushort)f2bf(v.z); o.w = (ushort)f2bf(v.w);
        ((ushort4*)y)[i] = o;
    }
}

// ---------------------------------------------------------------------------
__global__ void rope_table(float* __restrict__ cosT, float* __restrict__ sinT)
{
    int idx = blockIdx.x * 256 + threadIdx.x;
    int s = idx >> 6, i = idx & 63;
    float inv_f = (float)pow(1.0e6, -(double)i / 64.0);
    float freq  = (float)s * inv_f;
    cosT[idx] = (float)cos((double)freq);
    sinT[idx] = (float)sin((double)freq);
}

__global__ void rope_apply(float* __restrict__ X,
                           const float* __restrict__ cosT,
                           const float* __restrict__ sinT, int nh)
{
    int idx = blockIdx.x * 256 + threadIdx.x;
    int i = idx & 63;
    int t = idx >> 6;
    int h = t % nh;
    int row = t / nh;
    int s = row & (SEQ - 1);
    float c  = cosT[s*64 + i];
    float sv = sinT[s*64 + i];
    float* p = X + (size_t)row * (nh * HDIM) + h * HDIM;
    float x1 = p[i], x2 = p[i + 64];
    p[i]      = x1 * c - x2 * sv;
    p[i + 64] = x2 * c + x1 * sv;
}

__global__ void rope_apply_q(const float* __restrict__ Qf,
                             __hip_bfloat16* __restrict__ Qbf,
                             const float* __restrict__ cosT,
                             const float* __restrict__ sinT)
{
    int idx = blockIdx.x * 256 + threadIdx.x;
    int i = idx & 63;
    int t = idx >> 6;
    int h = t & 31;
    int row = t >> 5;
    int s = row & (SEQ - 1);
    const float scale = 0.08838834764831845f;
    float c  = cosT[s*64 + i];
    float sv = sinT[s*64 + i];
    const float* p = Qf + (size_t)row * 4096 + h * HDIM;
    float x1 = p[i], x2 = p[i + 64];
    __hip_bfloat16* q = Qbf + (size_t)row * 4096 + h * HDIM;
    q[i]      = __float2bfloat16((x1 * c - x2 * sv) * scale);
    q[i + 64] = __float2bfloat16((x2 * c + x1 * sv) * scale);
}

// ---------------------------------------------------------------------------
// PQ round-trip (fp32-exact distances).
// ---------------------------------------------------------------------------
__global__ __launch_bounds__(256) void pq_kernel(
    const float* __restrict__ X, const float* __restrict__ cent,
    __hip_bfloat16* __restrict__ rec)
{
    __shared__ float Cs[KSUB * DSUB];
    __shared__ float CC[KSUB];
    const int m = blockIdx.y;
    const float* cm = cent + (size_t)m * KSUB * DSUB;
    for (int t = threadIdx.x; t < KSUB * DSUB; t += 256) Cs[t] = cm[t];
    __syncthreads();
    {
        int k = threadIdx.x;
        float s = 0.f;
        #pragma unroll
        for (int d = 0; d < DSUB; d++) s += Cs[k*DSUB + d] * Cs[k*DSUB + d];
        CC[k] = s;
    }
    __syncthreads();

    int p  = blockIdx.x * 256 + threadIdx.x;
    int s_ = p & (SEQ - 1);
    int bh = p >> 10;
    int b  = bh >> 3, h = bh & 7;
    const float* x = X + (size_t)(b*SEQ + s_) * (NKV*HDIM) + h*HDIM + m*DSUB;

    float xv[DSUB], xx = 0.f;
    #pragma unroll
    for (int d = 0; d < DSUB; d++) { xv[d] = x[d]; xx += xv[d]*xv[d]; }

    float best = INFINITY; int bk = 0;
    for (int k = 0; k < KSUB; k++) {
        float dot = 0.f;
        #pragma unroll
        for (int d = 0; d < DSUB; d++) dot += xv[d] * Cs[k*DSUB + d];
        float d2 = xx + CC[k] - 2.f * dot;
        if (d2 < best) { best = d2; bk = k; }
    }

    __hip_bfloat16* r = rec + (size_t)(b*SEQ + s_) * (NKV*HDIM) + h*HDIM + m*DSUB;
    #pragma unroll
    for (int d = 0; d < DSUB; d++) r[d] = __float2bfloat16(Cs[bk*DSUB + d]);
}

// ---------------------------------------------------------------------------
// MFMA flash attention; output bf16 (feeds the bf16 O-proj directly).
// ---------------------------------------------------------------------------
__global__ __launch_bounds__(256) void attn_mfma(
    const short* __restrict__ Qbf, const short* __restrict__ K,
    const short* __restrict__ V, __hip_bfloat16* __restrict__ O)
{
    __shared__ short Ks[32 * 128];
    __shared__ short Vt[128 * 40];
    __shared__ short Ps[4 * 16 * 40];

    const int tid  = threadIdx.x;
    const int wid  = tid >> 6, lane = tid & 63;
    const int l15  = lane & 15, l4 = lane >> 4;
    const int qt   = gridDim.x - 1 - blockIdx.x;
    const int qb   = qt * 64;
    const int h    = blockIdx.y & 31, b = blockIdx.y >> 5;
    const int kvh  = h >> 2;
    const int qw   = qb + wid * 16;

    bf16x8 qf[4];
    {
        const short* qp = Qbf + (size_t)(b*SEQ + qw + l15) * 4096 + h*HDIM + l4*8;
        #pragma unroll
        for (int ks = 0; ks < 4; ks++) qf[ks] = *(const bf16x8*)(qp + 32*ks);
    }

    f32x4 o[8];
    #pragma unroll
    for (int i = 0; i < 8; i++) o[i] = (f32x4)0.f;
    float m[4]  = {-1e30f, -1e30f, -1e30f, -1e30f};
    float ls[4] = {0.f, 0.f, 0.f, 0.f};

    const int ntiles = 2 * (qt + 1);
    const short* Kg = K + (size_t)b * SEQ * 1024 + kvh * HDIM;
    const short* Vg = V + (size_t)b * SEQ * 1024 + kvh * HDIM;

    for (int t = 0; t < ntiles; t++) {
        const int jbase = t * 32;
        __syncthreads();
        {
            int j = tid >> 3, d0 = (tid & 7) * 16;
            const short* src = Kg + (size_t)(jbase + j) * 1024 + d0;
            bf16x8 a = *(const bf16x8*)src;
            bf16x8 c = *(const bf16x8*)(src + 8);
            int sw = (j & 7) << 3;
            *(bf16x8*)(Ks + j*128 + (d0 ^ sw))       = a;
            *(bf16x8*)(Ks + j*128 + ((d0 + 8) ^ sw)) = c;
        }
        {
            int j = tid & 31, e0 = (tid >> 5) * 16;
            const short* src = Vg + (size_t)(jbase + j) * 1024 + e0;
            bf16x8 a = *(const bf16x8*)src;
            bf16x8 c = *(const bf16x8*)(src + 8);
            #pragma unroll
            for (int i = 0; i < 8; i++) {
                Vt[(e0 + i)     * 40 + j] = a[i];
                Vt[(e0 + i + 8) * 40 + j] = c[i];
            }
        }
        __syncthreads();

        if (jbase >= qw + 16) continue;

        f32x4 sc0 = (f32x4)0.f, sc1 = (f32x4)0.f;
        #pragma unroll
        for (int ks = 0; ks < 4; ks++) {
            int d0 = 32*ks + l4*8;
            int j0 = l15, j1 = l15 + 16;
            bf16x8 kb0 = *(const bf16x8*)(Ks + j0*128 + (d0 ^ ((j0 & 7) << 3)));
            bf16x8 kb1 = *(const bf16x8*)(Ks + j1*128 + (d0 ^ ((j1 & 7) << 3)));
            sc0 = __builtin_amdgcn_mfma_f32_16x16x32_bf16(qf[ks], kb0, sc0, 0, 0, 0);
            sc1 = __builtin_amdgcn_mfma_f32_16x16x32_bf16(qf[ks], kb1, sc1, 0, 0, 0);
        }

        float mx[4];
        #pragma unroll
        for (int r = 0; r < 4; r++) {
            int q_r = qw + l4*4 + r;
            if (jbase + l15      > q_r) sc0[r] = -1e30f;
            if (jbase + 16 + l15 > q_r) sc1[r] = -1e30f;
            mx[r] = fmaxf(sc0[r], sc1[r]);
        }
        #pragma unroll
        for (int off = 1; off < 16; off <<= 1)
            #pragma unroll
            for (int r = 0; r < 4; r++)
                mx[r] = fmaxf(mx[r], __shfl_xor(mx[r], off, 64));

        #pragma unroll
        for (int r = 0; r < 4; r++) {
            float mn = fmaxf(m[r], mx[r]);
            float cf = __expf(m[r] - mn);
            m[r] = mn;
            float p0 = __expf(sc0[r] - mn);
            float p1 = __expf(sc1[r] - mn);
            ls[r] = ls[r] * cf + p0 + p1;
            #pragma unroll
            for (int dt = 0; dt < 8; dt++) o[dt][r] *= cf;
            Ps[wid*640 + (l4*4 + r)*40 + l15]      = f2bf(p0);
            Ps[wid*640 + (l4*4 + r)*40 + l15 + 16] = f2bf(p1);
        }

        bf16x8 pa = *(const bf16x8*)(Ps + wid*640 + l15*40 + l4*8);
        #pragma unroll
        for (int dt = 0; dt < 8; dt++) {
            bf16x8 vb = *(const bf16x8*)(Vt + (16*dt + l15)*40 + l4*8);
            o[dt] = __builtin_amdgcn_mfma_f32_16x16x32_bf16(pa, vb, o[dt], 0, 0, 0);
        }
    }

    #pragma unroll
    for (int off = 1; off < 16; off <<= 1)
        #pragma unroll
        for (int r = 0; r < 4; r++)
            ls[r] += __shfl_xor(ls[r], off, 64);

    __hip_bfloat16* Op = O + (size_t)(b*SEQ + qw + l4*4) * 4096 + h*HDIM + l15;
    #pragma unroll
    for (int r = 0; r < 4; r++) {
        float inv = 1.f / ls[r];
        #pragma unroll
        for (int dt = 0; dt < 8; dt++)
            Op[(size_t)r * 4096 + dt * 16] = __float2bfloat16(o[dt][r] * inv);
    }
}

// ---------------------------------------------------------------------------
extern "C" void kernel_launch(void* const* d_in, const int* in_sizes, int n_in,
                              void* d_out, int out_size, void* d_ws, size_t ws_size,
                              hipStream_t stream)
{
    const float* hs  = (const float*)d_in[0];
    const float* q_w = (const float*)d_in[1];
    const float* q_b = (const float*)d_in[2];
    const float* k_w = (const float*)d_in[3];
    const float* k_b = (const float*)d_in[4];
    const float* v_w = (const float*)d_in[5];
    const float* v_b = (const float*)d_in[6];
    const float* o_w = (const float*)d_in[7];
    const float* k_c = (const float*)d_in[8];
    const float* v_c = (const float*)d_in[9];
    float* out = (float*)d_out;

    // Workspace layout (total 92.8 MB, overlaid by liveness):
    //   [0,32M)      Qf fp32            -> AttnBf bf16 (16M) after rope_apply_q
    //   [32M,48M)    hs_bf (dead after Q-proj) -> Kf fp32 (8M) + ...
    //   [40M,48M)    ...                -> Vf fp32 (8M)
    //   [32M,48M)    ...                -> Qbf bf16 (16M) after PQ
    //   [48M,80M)    qw_bf (dead after Q-proj) -> ow_bf
    //   [80M,84M)    Krec   [84M,88M) Vrec   [88M,88.5M) cos/sin
    char* ws = (char*)d_ws;
    float*          Qf     = (float*)(ws);
    __hip_bfloat16* AttnBf = (__hip_bfloat16*)(ws);
    ushort*         hs_bf  = (ushort*)(ws + 33554432);
    float*          Kf     = (float*)(ws + 33554432);
    float*          Vf     = (float*)(ws + 41943040);
    __hip_bfloat16* Qbf    = (__hip_bfloat16*)(ws + 33554432);
    ushort*         qw_bf  = (ushort*)(ws + 50331648);
    ushort*         ow_bf  = (ushort*)(ws + 50331648);
    __hip_bfloat16* Krec   = (__hip_bfloat16*)(ws + 83886080);
    __hip_bfloat16* Vrec   = (__hip_bfloat16*)(ws + 88080384);
    float*          cosT   = (float*)(ws + 92274688);
    float*          sinT   = (float*)(ws + 92536832);

    const int Mrows = BATCH * SEQ;      // 2048

    rope_table<<<dim3(256), dim3(256), 0, stream>>>(cosT, sinT);

    // --- Q projection: bf16 MFMA ---
    cast_bf16<<<dim3(8192),  256, 0, stream>>>(hs,  hs_bf, 2097152);
    cast_bf16<<<dim3(16384), 256, 0, stream>>>(q_w, qw_bf, 4194304);
    gemm_mfma_bf16<<<dim3(32, 16), 256, 0, stream>>>(
        (const short*)hs_bf, (const short*)qw_bf, q_b, Qf, NH*HDIM, 4096);

    // --- K/V projections: fp32 (PQ argmin precision) ---
    gemm_bias<<<dim3(8, 16), 256, 0, stream>>>(hs, k_w, k_b, Kf, Mrows, NKV*HDIM, 4096);
    gemm_bias<<<dim3(8, 16), 256, 0, stream>>>(hs, v_w, v_b, Vf, Mrows, NKV*HDIM, 4096);

    rope_apply<<<dim3(4096), 256, 0, stream>>>(Kf, cosT, sinT, NKV);

    pq_kernel<<<dim3(64, PQM), 256, 0, stream>>>(Kf, k_c, Krec);
    pq_kernel<<<dim3(64, PQM), 256, 0, stream>>>(Vf, v_c, Vrec);

    // Kf/Vf dead: bf16 RoPE'd+scaled Q over their storage.
    rope_apply_q<<<dim3(16384), 256, 0, stream>>>(Qf, Qbf, cosT, sinT);

    // qw_bf dead: cast O weights over it.
    cast_bf16<<<dim3(16384), 256, 0, stream>>>(o_w, ow_bf, 4194304);

    // Qf dead: attention output (bf16) over it.
    attn_mfma<<<dim3(16, 64), 256, 0, stream>>>((const short*)Qbf, (const short*)Krec,
                                                (const short*)Vrec, AttnBf);

    // --- O projection: bf16 MFMA, fp32 out ---
    gemm_mfma_bf16<<<dim3(32, 16), 256, 0, stream>>>(
        (const short*)AttnBf, (const short*)ow_bf, nullptr, out, NH*HDIM, 4096);
}

// Round 4
// 600.669 us; speedup vs baseline: 9.2815x; 2.4253x over previous
//
#include <hip/hip_runtime.h>
#include <hip/hip_bf16.h>
#include <math.h>

#define NH   32
#define NKV  8
#define HDIM 128
#define BATCH 2
#define SEQ  1024
#define KSUB 256
#define DSUB 16
#define PQM  8

typedef __attribute__((ext_vector_type(8))) _Float16 f16x8;
typedef __attribute__((ext_vector_type(4))) _Float16 f16x4;
typedef __attribute__((ext_vector_type(8))) short bf16x8;
typedef __attribute__((ext_vector_type(4))) float f32x4;

__device__ inline short f2bf(float x) {
    unsigned u = __builtin_bit_cast(unsigned, x);
    unsigned r = (u + 0x7fff + ((u >> 16) & 1)) >> 16;
    return (short)r;
}

__device__ inline void gload_lds16(const void* g, void* l) {
    __builtin_amdgcn_global_load_lds(
        (const __attribute__((address_space(1))) unsigned*)g,
        (__attribute__((address_space(3))) unsigned*)l, 16, 0, 0);
}

// ---------------------------------------------------------------------------
// fp32 -> fp16 2-term split: x = hi + mid * 2^-12 (+ O(2^-24 |x|)).
// mid pre-scaled by 2^12 to stay in fp16 normal range.
// ---------------------------------------------------------------------------
__global__ void split_f16(const float* __restrict__ x,
                          _Float16* __restrict__ hi, _Float16* __restrict__ mid,
                          int n4)
{
    int i = blockIdx.x * 256 + threadIdx.x;
    if (i < n4) {
        float4 v = ((const float4*)x)[i];
        f16x4 h, m;
        h.x = (_Float16)v.x; m.x = (_Float16)((v.x - (float)h.x) * 4096.f);
        h.y = (_Float16)v.y; m.y = (_Float16)((v.y - (float)h.y) * 4096.f);
        h.z = (_Float16)v.z; m.z = (_Float16)((v.z - (float)h.z) * 4096.f);
        h.w = (_Float16)v.w; m.w = (_Float16)((v.w - (float)h.w) * 4096.f);
        ((f16x4*)hi)[i]  = h;
        ((f16x4*)mid)[i] = m;
    }
}

// single-term fp16 cast (Q/O weights)
__global__ void cast_f16(const float* __restrict__ x, _Float16* __restrict__ y, int n4)
{
    int i = blockIdx.x * 256 + threadIdx.x;
    if (i < n4) {
        float4 v = ((const float4*)x)[i];
        f16x4 h;
        h.x = (_Float16)v.x; h.y = (_Float16)v.y;
        h.z = (_Float16)v.z; h.w = (_Float16)v.w;
        ((f16x4*)y)[i] = h;
    }
}

// ---------------------------------------------------------------------------
// 1-pass fp16 MFMA GEMM: C[M x N] = A[M x K] @ W[N x K]^T + bias. fp32 out.
// 128x128 tile, BK=32, 4 waves, global_load_lds(16B), linear LDS.
// ---------------------------------------------------------------------------
__global__ __launch_bounds__(256) void gemm_f16_1p(
    const _Float16* __restrict__ A, const _Float16* __restrict__ W,
    const float* __restrict__ bias, float* __restrict__ C,
    int N, int K)
{
    __shared__ _Float16 Al[128 * 32];
    __shared__ _Float16 Bl[128 * 32];

    const int tid = threadIdx.x;
    const int wid = tid >> 6, lane = tid & 63;
    const int l15 = lane & 15, l4 = lane >> 4;
    const int row0 = blockIdx.y * 128, col0 = blockIdx.x * 128;
    const int wr = (wid >> 1) * 64, wc = (wid & 1) * 64;

    f32x4 acc[4][4];
    #pragma unroll
    for (int m = 0; m < 4; m++)
        #pragma unroll
        for (int n = 0; n < 4; n++) acc[m][n] = (f32x4)0.f;

    const int ci0 = tid, ci1 = tid + 256;
    const _Float16* Ag0 = A + (size_t)(row0 + (ci0 >> 2)) * K + (ci0 & 3) * 8;
    const _Float16* Ag1 = A + (size_t)(row0 + (ci1 >> 2)) * K + (ci1 & 3) * 8;
    const _Float16* Wg0 = W + (size_t)(col0 + (ci0 >> 2)) * K + (ci0 & 3) * 8;
    const _Float16* Wg1 = W + (size_t)(col0 + (ci1 >> 2)) * K + (ci1 & 3) * 8;

    for (int k0 = 0; k0 < K; k0 += 32) {
        __syncthreads();
        gload_lds16(Ag0 + k0, Al + ci0 * 8);
        gload_lds16(Ag1 + k0, Al + ci1 * 8);
        gload_lds16(Wg0 + k0, Bl + ci0 * 8);
        gload_lds16(Wg1 + k0, Bl + ci1 * 8);
        __syncthreads();

        f16x8 af[4], bfr[4];
        #pragma unroll
        for (int m = 0; m < 4; m++)
            af[m] = *(const f16x8*)(Al + (wr + m*16 + l15) * 32 + l4 * 8);
        #pragma unroll
        for (int n = 0; n < 4; n++)
            bfr[n] = *(const f16x8*)(Bl + (wc + n*16 + l15) * 32 + l4 * 8);
        #pragma unroll
        for (int m = 0; m < 4; m++)
            #pragma unroll
            for (int n = 0; n < 4; n++)
                acc[m][n] = __builtin_amdgcn_mfma_f32_16x16x32_f16(af[m], bfr[n], acc[m][n], 0, 0, 0);
    }

    float bv[4];
    #pragma unroll
    for (int n = 0; n < 4; n++)
        bv[n] = bias ? bias[col0 + wc + n*16 + l15] : 0.f;

    #pragma unroll
    for (int m = 0; m < 4; m++) {
        #pragma unroll
        for (int r = 0; r < 4; r++) {
            float* Cp = C + (size_t)(row0 + wr + m*16 + l4*4 + r) * N + col0 + wc + l15;
            #pragma unroll
            for (int n = 0; n < 4; n++)
                Cp[n * 16] = acc[m][n][r] + bv[n];
        }
    }
}

// ---------------------------------------------------------------------------
// 3-pass precision-split fp16 GEMM for fused K|V projection.
// C[2048][2048] = hs[2048][4096] @ [k_w;v_w]^T + bias, fp32-equivalent:
//   C = hi.HI + (hi.MID + mid.HI) * 2^-12   (mid.MID ~ 2^-24 dropped)
// 64x128 tile, BK=32, 4 waves (each 32x64), dual accumulators.
// ---------------------------------------------------------------------------
__global__ __launch_bounds__(256) void gemm_f16_3p(
    const _Float16* __restrict__ Ahi, const _Float16* __restrict__ Ami,
    const _Float16* __restrict__ Whi, const _Float16* __restrict__ Wmi,
    const float* __restrict__ bK, const float* __restrict__ bV,
    float* __restrict__ C)
{
    __shared__ _Float16 sAh[64 * 32];
    __shared__ _Float16 sAm[64 * 32];
    __shared__ _Float16 sWh[128 * 32];
    __shared__ _Float16 sWm[128 * 32];

    const int tid = threadIdx.x;
    const int wid = tid >> 6, lane = tid & 63;
    const int l15 = lane & 15, l4 = lane >> 4;
    const int row0 = blockIdx.y * 64, col0 = blockIdx.x * 128;
    const int wr = (wid >> 1) * 32, wc = (wid & 1) * 64;
    const int K = 4096;

    f32x4 am[2][4], ax[2][4];
    #pragma unroll
    for (int m = 0; m < 2; m++)
        #pragma unroll
        for (int n = 0; n < 4; n++) { am[m][n] = (f32x4)0.f; ax[m][n] = (f32x4)0.f; }

    // A: 64 rows x 32 cols = 256 x 16B chunks; W: 128 rows = 512 chunks
    const int rA = tid >> 2, kA = (tid & 3) * 8;
    const _Float16* Ah  = Ahi + (size_t)(row0 + rA) * K + kA;
    const _Float16* Am_ = Ami + (size_t)(row0 + rA) * K + kA;
    const _Float16* Wh0 = Whi + (size_t)(col0 + rA) * K + kA;
    const _Float16* Wh1 = Whi + (size_t)(col0 + 64 + rA) * K + kA;
    const _Float16* Wm0 = Wmi + (size_t)(col0 + rA) * K + kA;
    const _Float16* Wm1 = Wmi + (size_t)(col0 + 64 + rA) * K + kA;

    for (int k0 = 0; k0 < K; k0 += 32) {
        __syncthreads();
        gload_lds16(Ah  + k0, sAh + tid * 8);
        gload_lds16(Am_ + k0, sAm + tid * 8);
        gload_lds16(Wh0 + k0, sWh + tid * 8);
        gload_lds16(Wh1 + k0, sWh + (tid + 256) * 8);
        gload_lds16(Wm0 + k0, sWm + tid * 8);
        gload_lds16(Wm1 + k0, sWm + (tid + 256) * 8);
        __syncthreads();

        f16x8 ah[2], amv[2], bh[4], bm[4];
        #pragma unroll
        for (int m = 0; m < 2; m++) {
            ah[m]  = *(const f16x8*)(sAh + (wr + m*16 + l15) * 32 + l4 * 8);
            amv[m] = *(const f16x8*)(sAm + (wr + m*16 + l15) * 32 + l4 * 8);
        }
        #pragma unroll
        for (int n = 0; n < 4; n++) {
            bh[n] = *(const f16x8*)(sWh + (wc + n*16 + l15) * 32 + l4 * 8);
            bm[n] = *(const f16x8*)(sWm + (wc + n*16 + l15) * 32 + l4 * 8);
        }
        #pragma unroll
        for (int m = 0; m < 2; m++)
            #pragma unroll
            for (int n = 0; n < 4; n++) {
                am[m][n] = __builtin_amdgcn_mfma_f32_16x16x32_f16(ah[m],  bh[n], am[m][n], 0, 0, 0);
                ax[m][n] = __builtin_amdgcn_mfma_f32_16x16x32_f16(ah[m],  bm[n], ax[m][n], 0, 0, 0);
                ax[m][n] = __builtin_amdgcn_mfma_f32_16x16x32_f16(amv[m], bh[n], ax[m][n], 0, 0, 0);
            }
    }

    const float s = 1.f / 4096.f;
    #pragma unroll
    for (int m = 0; m < 2; m++) {
        #pragma unroll
        for (int r = 0; r < 4; r++) {
            float* Cp = C + (size_t)(row0 + wr + m*16 + l4*4 + r) * 2048 + col0 + wc + l15;
            #pragma unroll
            for (int n = 0; n < 4; n++) {
                int col = col0 + wc + n*16 + l15;
                float b = (col < 1024) ? bK[col] : bV[col - 1024];
                Cp[n * 16] = am[m][n][r] + ax[m][n][r] * s + b;
            }
        }
    }
}

// ---------------------------------------------------------------------------
__global__ void rope_table(float* __restrict__ cosT, float* __restrict__ sinT)
{
    int idx = blockIdx.x * 256 + threadIdx.x;
    int s = idx >> 6, i = idx & 63;
    float inv_f = (float)pow(1.0e6, -(double)i / 64.0);
    float freq  = (float)s * inv_f;
    cosT[idx] = (float)cos((double)freq);
    sinT[idx] = (float)sin((double)freq);
}

// in-place fp32 RoPE with row stride ldx (for K inside the fused KV buffer)
__global__ void rope_apply(float* __restrict__ X,
                           const float* __restrict__ cosT,
                           const float* __restrict__ sinT, int nh, int ldx)
{
    int idx = blockIdx.x * 256 + threadIdx.x;
    int i = idx & 63;
    int t = idx >> 6;
    int h = t % nh;
    int row = t / nh;
    int s = row & (SEQ - 1);
    float c  = cosT[s*64 + i];
    float sv = sinT[s*64 + i];
    float* p = X + (size_t)row * ldx + h * HDIM;
    float x1 = p[i], x2 = p[i + 64];
    p[i]      = x1 * c - x2 * sv;
    p[i + 64] = x2 * c + x1 * sv;
}

__global__ void rope_apply_q(const float* __restrict__ Qf,
                             __hip_bfloat16* __restrict__ Qbf,
                             const float* __restrict__ cosT,
                             const float* __restrict__ sinT)
{
    int idx = blockIdx.x * 256 + threadIdx.x;
    int i = idx & 63;
    int t = idx >> 6;
    int h = t & 31;
    int row = t >> 5;
    int s = row & (SEQ - 1);
    const float scale = 0.08838834764831845f;
    float c  = cosT[s*64 + i];
    float sv = sinT[s*64 + i];
    const float* p = Qf + (size_t)row * 4096 + h * HDIM;
    float x1 = p[i], x2 = p[i + 64];
    __hip_bfloat16* q = Qbf + (size_t)row * 4096 + h * HDIM;
    q[i]      = __float2bfloat16((x1 * c - x2 * sv) * scale);
    q[i + 64] = __float2bfloat16((x2 * c + x1 * sv) * scale);
}

// ---------------------------------------------------------------------------
// PQ round-trip (fp32-exact distances). X row stride ldx.
// ---------------------------------------------------------------------------
__global__ __launch_bounds__(256) void pq_kernel(
    const float* __restrict__ X, const float* __restrict__ cent,
    __hip_bfloat16* __restrict__ rec, int ldx)
{
    __shared__ float Cs[KSUB * DSUB];
    __shared__ float CC[KSUB];
    const int m = blockIdx.y;
    const float* cm = cent + (size_t)m * KSUB * DSUB;
    for (int t = threadIdx.x; t < KSUB * DSUB; t += 256) Cs[t] = cm[t];
    __syncthreads();
    {
        int k = threadIdx.x;
        float s = 0.f;
        #pragma unroll
        for (int d = 0; d < DSUB; d++) s += Cs[k*DSUB + d] * Cs[k*DSUB + d];
        CC[k] = s;
    }
    __syncthreads();

    int p  = blockIdx.x * 256 + threadIdx.x;
    int s_ = p & (SEQ - 1);
    int bh = p >> 10;
    int b  = bh >> 3, h = bh & 7;
    const float* x = X + (size_t)(b*SEQ + s_) * ldx + h*HDIM + m*DSUB;

    float xv[DSUB], xx = 0.f;
    #pragma unroll
    for (int d = 0; d < DSUB; d++) { xv[d] = x[d]; xx += xv[d]*xv[d]; }

    float best = INFINITY; int bk = 0;
    for (int k = 0; k < KSUB; k++) {
        float dot = 0.f;
        #pragma unroll
        for (int d = 0; d < DSUB; d++) dot += xv[d] * Cs[k*DSUB + d];
        float d2 = xx + CC[k] - 2.f * dot;
        if (d2 < best) { best = d2; bk = k; }
    }

    __hip_bfloat16* r = rec + (size_t)(b*SEQ + s_) * (NKV*HDIM) + h*HDIM + m*DSUB;
    #pragma unroll
    for (int d = 0; d < DSUB; d++) r[d] = __float2bfloat16(Cs[bk*DSUB + d]);
}

// ---------------------------------------------------------------------------
// MFMA flash attention; output fp16 (feeds the f16 O-proj directly).
// ---------------------------------------------------------------------------
__global__ __launch_bounds__(256) void attn_mfma(
    const short* __restrict__ Qbf, const short* __restrict__ K,
    const short* __restrict__ V, _Float16* __restrict__ O)
{
    __shared__ short Ks[32 * 128];
    __shared__ short Vt[128 * 40];
    __shared__ short Ps[4 * 16 * 40];

    const int tid  = threadIdx.x;
    const int wid  = tid >> 6, lane = tid & 63;
    const int l15  = lane & 15, l4 = lane >> 4;
    const int qt   = gridDim.x - 1 - blockIdx.x;
    const int qb   = qt * 64;
    const int h    = blockIdx.y & 31, b = blockIdx.y >> 5;
    const int kvh  = h >> 2;
    const int qw   = qb + wid * 16;

    bf16x8 qf[4];
    {
        const short* qp = Qbf + (size_t)(b*SEQ + qw + l15) * 4096 + h*HDIM + l4*8;
        #pragma unroll
        for (int ks = 0; ks < 4; ks++) qf[ks] = *(const bf16x8*)(qp + 32*ks);
    }

    f32x4 o[8];
    #pragma unroll
    for (int i = 0; i < 8; i++) o[i] = (f32x4)0.f;
    float m[4]  = {-1e30f, -1e30f, -1e30f, -1e30f};
    float ls[4] = {0.f, 0.f, 0.f, 0.f};

    const int ntiles = 2 * (qt + 1);
    const short* Kg = K + (size_t)b * SEQ * 1024 + kvh * HDIM;
    const short* Vg = V + (size_t)b * SEQ * 1024 + kvh * HDIM;

    for (int t = 0; t < ntiles; t++) {
        const int jbase = t * 32;
        __syncthreads();
        {
            int j = tid >> 3, d0 = (tid & 7) * 16;
            const short* src = Kg + (size_t)(jbase + j) * 1024 + d0;
            bf16x8 a = *(const bf16x8*)src;
            bf16x8 c = *(const bf16x8*)(src + 8);
            int sw = (j & 7) << 3;
            *(bf16x8*)(Ks + j*128 + (d0 ^ sw))       = a;
            *(bf16x8*)(Ks + j*128 + ((d0 + 8) ^ sw)) = c;
        }
        {
            int j = tid & 31, e0 = (tid >> 5) * 16;
            const short* src = Vg + (size_t)(jbase + j) * 1024 + e0;
            bf16x8 a = *(const bf16x8*)src;
            bf16x8 c = *(const bf16x8*)(src + 8);
            #pragma unroll
            for (int i = 0; i < 8; i++) {
                Vt[(e0 + i)     * 40 + j] = a[i];
                Vt[(e0 + i + 8) * 40 + j] = c[i];
            }
        }
        __syncthreads();

        if (jbase >= qw + 16) continue;

        f32x4 sc0 = (f32x4)0.f, sc1 = (f32x4)0.f;
        #pragma unroll
        for (int ks = 0; ks < 4; ks++) {
            int d0 = 32*ks + l4*8;
            int j0 = l15, j1 = l15 + 16;
            bf16x8 kb0 = *(const bf16x8*)(Ks + j0*128 + (d0 ^ ((j0 & 7) << 3)));
            bf16x8 kb1 = *(const bf16x8*)(Ks + j1*128 + (d0 ^ ((j1 & 7) << 3)));
            sc0 = __builtin_amdgcn_mfma_f32_16x16x32_bf16(qf[ks], kb0, sc0, 0, 0, 0);
            sc1 = __builtin_amdgcn_mfma_f32_16x16x32_bf16(qf[ks], kb1, sc1, 0, 0, 0);
        }

        float mx[4];
        #pragma unroll
        for (int r = 0; r < 4; r++) {
            int q_r = qw + l4*4 + r;
            if (jbase + l15      > q_r) sc0[r] = -1e30f;
            if (jbase + 16 + l15 > q_r) sc1[r] = -1e30f;
            mx[r] = fmaxf(sc0[r], sc1[r]);
        }
        #pragma unroll
        for (int off = 1; off < 16; off <<= 1)
            #pragma unroll
            for (int r = 0; r < 4; r++)
                mx[r] = fmaxf(mx[r], __shfl_xor(mx[r], off, 64));

        #pragma unroll
        for (int r = 0; r < 4; r++) {
            float mn = fmaxf(m[r], mx[r]);
            float cf = __expf(m[r] - mn);
            m[r] = mn;
            float p0 = __expf(sc0[r] - mn);
            float p1 = __expf(sc1[r] - mn);
            ls[r] = ls[r] * cf + p0 + p1;
            #pragma unroll
            for (int dt = 0; dt < 8; dt++) o[dt][r] *= cf;
            Ps[wid*640 + (l4*4 + r)*40 + l15]      = f2bf(p0);
            Ps[wid*640 + (l4*4 + r)*40 + l15 + 16] = f2bf(p1);
        }

        bf16x8 pa = *(const bf16x8*)(Ps + wid*640 + l15*40 + l4*8);
        #pragma unroll
        for (int dt = 0; dt < 8; dt++) {
            bf16x8 vb = *(const bf16x8*)(Vt + (16*dt + l15)*40 + l4*8);
            o[dt] = __builtin_amdgcn_mfma_f32_16x16x32_bf16(pa, vb, o[dt], 0, 0, 0);
        }
    }

    #pragma unroll
    for (int off = 1; off < 16; off <<= 1)
        #pragma unroll
        for (int r = 0; r < 4; r++)
            ls[r] += __shfl_xor(ls[r], off, 64);

    _Float16* Op = O + (size_t)(b*SEQ + qw + l4*4) * 4096 + h*HDIM + l15;
    #pragma unroll
    for (int r = 0; r < 4; r++) {
        float inv = 1.f / ls[r];
        #pragma unroll
        for (int dt = 0; dt < 8; dt++)
            Op[(size_t)r * 4096 + dt * 16] = (_Float16)(o[dt][r] * inv);
    }
}

// ---------------------------------------------------------------------------
extern "C" void kernel_launch(void* const* d_in, const int* in_sizes, int n_in,
                              void* d_out, int out_size, void* d_ws, size_t ws_size,
                              hipStream_t stream)
{
    const float* hs  = (const float*)d_in[0];
    const float* q_w = (const float*)d_in[1];
    const float* q_b = (const float*)d_in[2];
    const float* k_w = (const float*)d_in[3];
    const float* k_b = (const float*)d_in[4];
    const float* v_w = (const float*)d_in[5];
    const float* v_b = (const float*)d_in[6];
    const float* o_w = (const float*)d_in[7];
    const float* k_c = (const float*)d_in[8];
    const float* v_c = (const float*)d_in[9];
    float* out = (float*)d_out;

    // Workspace overlay (peak 88.5 MiB), MiB offsets by liveness phase:
    //  KV phase:  hs_hi[0,16) hs_mid[16,32) kvw_hi[32,48) kvw_mid[48,64)
    //             KVf[64,80) Krec[80,84) Vrec[84,88) trig[88,88.5)
    //  Q phase:   qw_f16[16,48)  Qf[48,80)        (hs_hi still live)
    //  attn/O:    Qbf[0,16)  AttnH[16,32)  ow_f16[32,64)
    char* ws = (char*)d_ws;
    _Float16*       hs_hi  = (_Float16*)(ws);
    _Float16*       hs_mid = (_Float16*)(ws + 16777216);
    _Float16*       kvw_hi = (_Float16*)(ws + 33554432);
    _Float16*       kvw_mid= (_Float16*)(ws + 50331648);
    float*          KVf    = (float*)(ws + 67108864);
    __hip_bfloat16* Krec   = (__hip_bfloat16*)(ws + 83886080);
    __hip_bfloat16* Vrec   = (__hip_bfloat16*)(ws + 88080384);
    float*          cosT   = (float*)(ws + 92274688);
    float*          sinT   = (float*)(ws + 92536832);
    _Float16*       qw_f16 = (_Float16*)(ws + 16777216);
    float*          Qf     = (float*)(ws + 50331648);
    __hip_bfloat16* Qbf    = (__hip_bfloat16*)(ws);
    _Float16*       AttnH  = (_Float16*)(ws + 16777216);
    _Float16*       ow_f16 = (_Float16*)(ws + 33554432);

    rope_table<<<dim3(256), dim3(256), 0, stream>>>(cosT, sinT);

    // --- splits: hs (2048x4096), k_w|v_w concatenated (2048x4096) ---
    split_f16<<<dim3(8192), 256, 0, stream>>>(hs, hs_hi, hs_mid, 2097152);
    split_f16<<<dim3(4096), 256, 0, stream>>>(k_w, kvw_hi, kvw_mid, 1048576);
    split_f16<<<dim3(4096), 256, 0, stream>>>(v_w, kvw_hi + (size_t)1024*4096,
                                              kvw_mid + (size_t)1024*4096, 1048576);

    // --- fused K|V projection, fp32-equivalent 3-pass ---
    gemm_f16_3p<<<dim3(16, 32), 256, 0, stream>>>(hs_hi, hs_mid, kvw_hi, kvw_mid,
                                                  k_b, v_b, KVf);

    // K part: RoPE in place (stride 2048)
    rope_apply<<<dim3(4096), 256, 0, stream>>>(KVf, cosT, sinT, NKV, 2048);

    pq_kernel<<<dim3(64, PQM), 256, 0, stream>>>(KVf,        k_c, Krec, 2048);
    pq_kernel<<<dim3(64, PQM), 256, 0, stream>>>(KVf + 1024, v_c, Vrec, 2048);

    // --- Q projection (hs_mid/kvw dead -> qw_f16, Qf) ---
    cast_f16<<<dim3(16384), 256, 0, stream>>>(q_w, qw_f16, 4194304);
    gemm_f16_1p<<<dim3(32, 16), 256, 0, stream>>>(hs_hi, qw_f16, q_b, Qf, NH*HDIM, 4096);

    // hs_hi dead -> Qbf
    rope_apply_q<<<dim3(16384), 256, 0, stream>>>(Qf, Qbf, cosT, sinT);

    // Qf dead -> ow_f16
    cast_f16<<<dim3(16384), 256, 0, stream>>>(o_w, ow_f16, 4194304);

    // qw dead -> AttnH
    attn_mfma<<<dim3(16, 64), 256, 0, stream>>>((const short*)Qbf, (const short*)Krec,
                                                (const short*)Vrec, AttnH);

    gemm_f16_1p<<<dim3(32, 16), 256, 0, stream>>>(AttnH, ow_f16, nullptr, out, NH*HDIM, 4096);
}

// Round 5
// 554.455 us; speedup vs baseline: 10.0552x; 1.0834x over previous
//
#include <hip/hip_runtime.h>
#include <hip/hip_bf16.h>
#include <math.h>

#define NH   32
#define NKV  8
#define HDIM 128
#define BATCH 2
#define SEQ  1024
#define KSUB 256
#define DSUB 16
#define PQM  8

typedef __attribute__((ext_vector_type(8))) _Float16 f16x8;
typedef __attribute__((ext_vector_type(8))) short bf16x8;
typedef __attribute__((ext_vector_type(4))) float f32x4;

__device__ inline short f2bf(float x) {
    unsigned u = __builtin_bit_cast(unsigned, x);
    unsigned r = (u + 0x7fff + ((u >> 16) & 1)) >> 16;
    return (short)r;
}

__device__ inline void gload_lds16(const void* g, void* l) {
    __builtin_amdgcn_global_load_lds(
        (const __attribute__((address_space(1))) unsigned*)g,
        (__attribute__((address_space(3))) unsigned*)l, 16, 0, 0);
}

// ---------------------------------------------------------------------------
// fp32 -> fp16 2-term split, 8 elems/thread: x = hi + mid * 2^-12.
// ---------------------------------------------------------------------------
__global__ void split_f16(const float* __restrict__ x,
                          _Float16* __restrict__ hi, _Float16* __restrict__ mid,
                          int n8)
{
    int i = blockIdx.x * 256 + threadIdx.x;
    if (i < n8) {
        float4 v0 = ((const float4*)x)[2*i];
        float4 v1 = ((const float4*)x)[2*i + 1];
        float v[8] = {v0.x, v0.y, v0.z, v0.w, v1.x, v1.y, v1.z, v1.w};
        f16x8 h, m;
        #pragma unroll
        for (int j = 0; j < 8; j++) {
            _Float16 hh = (_Float16)v[j];
            h[j] = hh;
            m[j] = (_Float16)((v[j] - (float)hh) * 4096.f);
        }
        ((f16x8*)hi)[i]  = h;
        ((f16x8*)mid)[i] = m;
    }
}

// single-term fp16 cast, 8 elems/thread
__global__ void cast_f16(const float* __restrict__ x, _Float16* __restrict__ y, int n8)
{
    int i = blockIdx.x * 256 + threadIdx.x;
    if (i < n8) {
        float4 v0 = ((const float4*)x)[2*i];
        float4 v1 = ((const float4*)x)[2*i + 1];
        float v[8] = {v0.x, v0.y, v0.z, v0.w, v1.x, v1.y, v1.z, v1.w};
        f16x8 h;
        #pragma unroll
        for (int j = 0; j < 8; j++) h[j] = (_Float16)v[j];
        ((f16x8*)y)[i] = h;
    }
}

// ---------------------------------------------------------------------------
// KV projection, 3-pass precision-split, split-K=2.
// 128x128 tile, 4 waves (2x2, each 64x64), BK=32. Partials (no bias) to
// Cp[kz][2048][2048]; Cp = am + ax*2^-12 per split.
// ---------------------------------------------------------------------------
__global__ __launch_bounds__(256, 2) void gemm_kv_3p(
    const _Float16* __restrict__ Ahi, const _Float16* __restrict__ Ami,
    const _Float16* __restrict__ Whi, const _Float16* __restrict__ Wmi,
    float* __restrict__ Cp)
{
    __shared__ _Float16 sAh[128 * 32];
    __shared__ _Float16 sAm[128 * 32];
    __shared__ _Float16 sWh[128 * 32];
    __shared__ _Float16 sWm[128 * 32];

    const int tid = threadIdx.x;
    const int wid = tid >> 6, lane = tid & 63;
    const int l15 = lane & 15, l4 = lane >> 4;
    const int col0 = blockIdx.x * 128, row0 = blockIdx.y * 128;
    const int kz = blockIdx.z;
    const int wr = (wid >> 1) * 64, wc = (wid & 1) * 64;

    f32x4 am[4][4], ax[4][4];
    #pragma unroll
    for (int m = 0; m < 4; m++)
        #pragma unroll
        for (int n = 0; n < 4; n++) { am[m][n] = (f32x4)0.f; ax[m][n] = (f32x4)0.f; }

    // chunk ci in [0,512): row = ci>>2, k = (ci&3)*8
    const int ci0 = tid, ci1 = tid + 256;
    const size_t kb = (size_t)kz * 2048;
    const _Float16* pAh0 = Ahi + (size_t)(row0 + (ci0 >> 2)) * 4096 + kb + (ci0 & 3) * 8;
    const _Float16* pAh1 = Ahi + (size_t)(row0 + (ci1 >> 2)) * 4096 + kb + (ci1 & 3) * 8;
    const _Float16* pAm0 = Ami + (size_t)(row0 + (ci0 >> 2)) * 4096 + kb + (ci0 & 3) * 8;
    const _Float16* pAm1 = Ami + (size_t)(row0 + (ci1 >> 2)) * 4096 + kb + (ci1 & 3) * 8;
    const _Float16* pWh0 = Whi + (size_t)(col0 + (ci0 >> 2)) * 4096 + kb + (ci0 & 3) * 8;
    const _Float16* pWh1 = Whi + (size_t)(col0 + (ci1 >> 2)) * 4096 + kb + (ci1 & 3) * 8;
    const _Float16* pWm0 = Wmi + (size_t)(col0 + (ci0 >> 2)) * 4096 + kb + (ci0 & 3) * 8;
    const _Float16* pWm1 = Wmi + (size_t)(col0 + (ci1 >> 2)) * 4096 + kb + (ci1 & 3) * 8;

    for (int k0 = 0; k0 < 2048; k0 += 32) {
        __syncthreads();
        gload_lds16(pAh0 + k0, sAh + ci0 * 8);
        gload_lds16(pAh1 + k0, sAh + ci1 * 8);
        gload_lds16(pAm0 + k0, sAm + ci0 * 8);
        gload_lds16(pAm1 + k0, sAm + ci1 * 8);
        gload_lds16(pWh0 + k0, sWh + ci0 * 8);
        gload_lds16(pWh1 + k0, sWh + ci1 * 8);
        gload_lds16(pWm0 + k0, sWm + ci0 * 8);
        gload_lds16(pWm1 + k0, sWm + ci1 * 8);
        __syncthreads();

        f16x8 ah[4], amv[4], bh[4], bm[4];
        #pragma unroll
        for (int m = 0; m < 4; m++) {
            ah[m]  = *(const f16x8*)(sAh + (wr + m*16 + l15) * 32 + l4 * 8);
            amv[m] = *(const f16x8*)(sAm + (wr + m*16 + l15) * 32 + l4 * 8);
        }
        #pragma unroll
        for (int n = 0; n < 4; n++) {
            bh[n] = *(const f16x8*)(sWh + (wc + n*16 + l15) * 32 + l4 * 8);
            bm[n] = *(const f16x8*)(sWm + (wc + n*16 + l15) * 32 + l4 * 8);
        }
        #pragma unroll
        for (int m = 0; m < 4; m++)
            #pragma unroll
            for (int n = 0; n < 4; n++) {
                am[m][n] = __builtin_amdgcn_mfma_f32_16x16x32_f16(ah[m],  bh[n], am[m][n], 0, 0, 0);
                ax[m][n] = __builtin_amdgcn_mfma_f32_16x16x32_f16(ah[m],  bm[n], ax[m][n], 0, 0, 0);
                ax[m][n] = __builtin_amdgcn_mfma_f32_16x16x32_f16(amv[m], bh[n], ax[m][n], 0, 0, 0);
            }
    }

    float* base = Cp + (size_t)kz * 2048 * 2048;
    const float s = 1.f / 4096.f;
    #pragma unroll
    for (int m = 0; m < 4; m++) {
        #pragma unroll
        for (int r = 0; r < 4; r++) {
            float* p = base + (size_t)(row0 + wr + m*16 + l4*4 + r) * 2048 + col0 + wc + l15;
            #pragma unroll
            for (int n = 0; n < 4; n++)
                p[n * 16] = am[m][n][r] + ax[m][n][r] * s;
        }
    }
}

// ---------------------------------------------------------------------------
// Split-K reduce + bias, fused K-RoPE. In-place into partial 0 (= KVf).
// grid (4096, 2): y=0 -> K half (rope pairs), y=1 -> V half.
// ---------------------------------------------------------------------------
__global__ void kv_reduce(float* __restrict__ KVp,
                          const float* __restrict__ bK, const float* __restrict__ bV,
                          const float* __restrict__ cosT, const float* __restrict__ sinT)
{
    int t = blockIdx.x * 256 + threadIdx.x;     // 0 .. 1048575
    float* P0 = KVp;
    const float* P1 = KVp + (size_t)2048 * 2048;
    if (blockIdx.y == 0) {
        int i  = t & 63;
        int h  = (t >> 6) & 7;
        int rr = t >> 9;
        int s  = rr & (SEQ - 1);
        size_t o = (size_t)rr * 2048 + h * 128 + i;
        float x1 = P0[o]      + P1[o]      + bK[h*128 + i];
        float x2 = P0[o + 64] + P1[o + 64] + bK[h*128 + i + 64];
        float c  = cosT[s*64 + i];
        float sv = sinT[s*64 + i];
        P0[o]      = x1 * c - x2 * sv;
        P0[o + 64] = x2 * c + x1 * sv;
    } else {
        int j  = t & 511;
        int rr = t >> 9;
        size_t o = (size_t)rr * 2048 + 1024 + j;
        P0[o]       = P0[o]       + P1[o]       + bV[j];
        P0[o + 512] = P0[o + 512] + P1[o + 512] + bV[j + 512];
    }
}

// ---------------------------------------------------------------------------
// Q projection with fused RoPE + scale + bf16 output.
// 128x128 tile, 4 waves 2x2 (64x64 each), BK=32. Wave frag cols remapped to
// {wc, wc+16, wc+64, wc+80} so rope pair (i, i+64) is in-thread (BN=128=head).
// ---------------------------------------------------------------------------
__global__ __launch_bounds__(256) void gemm_q_rope(
    const _Float16* __restrict__ A, const _Float16* __restrict__ W,
    const float* __restrict__ bias, __hip_bfloat16* __restrict__ Qbf,
    const float* __restrict__ cosT, const float* __restrict__ sinT)
{
    __shared__ _Float16 Al[128 * 32];
    __shared__ _Float16 Bl[128 * 32];

    const int tid = threadIdx.x;
    const int wid = tid >> 6, lane = tid & 63;
    const int l15 = lane & 15, l4 = lane >> 4;
    const int row0 = blockIdx.y * 128, col0 = blockIdx.x * 128;
    const int wr = (wid >> 1) * 64, wc = (wid & 1) * 32;
    const int K = 4096;

    f32x4 acc[4][4];
    #pragma unroll
    for (int m = 0; m < 4; m++)
        #pragma unroll
        for (int n = 0; n < 4; n++) acc[m][n] = (f32x4)0.f;

    const int ci0 = tid, ci1 = tid + 256;
    const _Float16* Ag0 = A + (size_t)(row0 + (ci0 >> 2)) * K + (ci0 & 3) * 8;
    const _Float16* Ag1 = A + (size_t)(row0 + (ci1 >> 2)) * K + (ci1 & 3) * 8;
    const _Float16* Wg0 = W + (size_t)(col0 + (ci0 >> 2)) * K + (ci0 & 3) * 8;
    const _Float16* Wg1 = W + (size_t)(col0 + (ci1 >> 2)) * K + (ci1 & 3) * 8;

    for (int k0 = 0; k0 < K; k0 += 32) {
        __syncthreads();
        gload_lds16(Ag0 + k0, Al + ci0 * 8);
        gload_lds16(Ag1 + k0, Al + ci1 * 8);
        gload_lds16(Wg0 + k0, Bl + ci0 * 8);
        gload_lds16(Wg1 + k0, Bl + ci1 * 8);
        __syncthreads();

        f16x8 af[4], bfr[4];
        #pragma unroll
        for (int m = 0; m < 4; m++)
            af[m] = *(const f16x8*)(Al + (wr + m*16 + l15) * 32 + l4 * 8);
        #pragma unroll
        for (int n = 0; n < 4; n++) {
            int fc = wc + (n & 1) * 16 + (n >> 1) * 64;
            bfr[n] = *(const f16x8*)(Bl + (fc + l15) * 32 + l4 * 8);
        }
        #pragma unroll
        for (int m = 0; m < 4; m++)
            #pragma unroll
            for (int n = 0; n < 4; n++)
                acc[m][n] = __builtin_amdgcn_mfma_f32_16x16x32_f16(af[m], bfr[n], acc[m][n], 0, 0, 0);
    }

    const float scale = 0.08838834764831845f;   // 1/sqrt(128)
    #pragma unroll
    for (int m = 0; m < 4; m++) {
        #pragma unroll
        for (int r = 0; r < 4; r++) {
            int rr = row0 + wr + m*16 + l4*4 + r;
            int s  = rr & (SEQ - 1);
            #pragma unroll
            for (int n = 0; n < 2; n++) {
                int i = wc + n*16 + l15;                 // [0,64)
                float x1 = acc[m][n][r]     + bias[col0 + i];
                float x2 = acc[m][n + 2][r] + bias[col0 + i + 64];
                float c  = cosT[s*64 + i];
                float sv = sinT[s*64 + i];
                Qbf[(size_t)rr * 4096 + col0 + i]      = __float2bfloat16((x1*c - x2*sv) * scale);
                Qbf[(size_t)rr * 4096 + col0 + i + 64] = __float2bfloat16((x2*c + x1*sv) * scale);
            }
        }
    }
}

// ---------------------------------------------------------------------------
// 1-pass fp16 MFMA GEMM (O projection): C = A @ W^T, fp32 out, no bias.
// ---------------------------------------------------------------------------
__global__ __launch_bounds__(256) void gemm_f16_1p(
    const _Float16* __restrict__ A, const _Float16* __restrict__ W,
    float* __restrict__ C, int N, int K)
{
    __shared__ _Float16 Al[128 * 32];
    __shared__ _Float16 Bl[128 * 32];

    const int tid = threadIdx.x;
    const int wid = tid >> 6, lane = tid & 63;
    const int l15 = lane & 15, l4 = lane >> 4;
    const int row0 = blockIdx.y * 128, col0 = blockIdx.x * 128;
    const int wr = (wid >> 1) * 64, wc = (wid & 1) * 64;

    f32x4 acc[4][4];
    #pragma unroll
    for (int m = 0; m < 4; m++)
        #pragma unroll
        for (int n = 0; n < 4; n++) acc[m][n] = (f32x4)0.f;

    const int ci0 = tid, ci1 = tid + 256;
    const _Float16* Ag0 = A + (size_t)(row0 + (ci0 >> 2)) * K + (ci0 & 3) * 8;
    const _Float16* Ag1 = A + (size_t)(row0 + (ci1 >> 2)) * K + (ci1 & 3) * 8;
    const _Float16* Wg0 = W + (size_t)(col0 + (ci0 >> 2)) * K + (ci0 & 3) * 8;
    const _Float16* Wg1 = W + (size_t)(col0 + (ci1 >> 2)) * K + (ci1 & 3) * 8;

    for (int k0 = 0; k0 < K; k0 += 32) {
        __syncthreads();
        gload_lds16(Ag0 + k0, Al + ci0 * 8);
        gload_lds16(Ag1 + k0, Al + ci1 * 8);
        gload_lds16(Wg0 + k0, Bl + ci0 * 8);
        gload_lds16(Wg1 + k0, Bl + ci1 * 8);
        __syncthreads();

        f16x8 af[4], bfr[4];
        #pragma unroll
        for (int m = 0; m < 4; m++)
            af[m] = *(const f16x8*)(Al + (wr + m*16 + l15) * 32 + l4 * 8);
        #pragma unroll
        for (int n = 0; n < 4; n++)
            bfr[n] = *(const f16x8*)(Bl + (wc + n*16 + l15) * 32 + l4 * 8);
        #pragma unroll
        for (int m = 0; m < 4; m++)
            #pragma unroll
            for (int n = 0; n < 4; n++)
                acc[m][n] = __builtin_amdgcn_mfma_f32_16x16x32_f16(af[m], bfr[n], acc[m][n], 0, 0, 0);
    }

    #pragma unroll
    for (int m = 0; m < 4; m++) {
        #pragma unroll
        for (int r = 0; r < 4; r++) {
            float* Cp = C + (size_t)(row0 + wr + m*16 + l4*4 + r) * N + col0 + wc + l15;
            #pragma unroll
            for (int n = 0; n < 4; n++)
                Cp[n * 16] = acc[m][n][r];
        }
    }
}

// ---------------------------------------------------------------------------
__global__ void rope_table(float* __restrict__ cosT, float* __restrict__ sinT)
{
    int idx = blockIdx.x * 256 + threadIdx.x;
    int s = idx >> 6, i = idx & 63;
    float inv_f = (float)pow(1.0e6, -(double)i / 64.0);
    float freq  = (float)s * inv_f;
    cosT[idx] = (float)cos((double)freq);
    sinT[idx] = (float)sin((double)freq);
}

// ---------------------------------------------------------------------------
// PQ round-trip (fp32-exact distances). X row stride ldx.
// ---------------------------------------------------------------------------
__global__ __launch_bounds__(256) void pq_kernel(
    const float* __restrict__ X, const float* __restrict__ cent,
    __hip_bfloat16* __restrict__ rec, int ldx)
{
    __shared__ float Cs[KSUB * DSUB];
    __shared__ float CC[KSUB];
    const int m = blockIdx.y;
    const float* cm = cent + (size_t)m * KSUB * DSUB;
    for (int t = threadIdx.x; t < KSUB * DSUB; t += 256) Cs[t] = cm[t];
    __syncthreads();
    {
        int k = threadIdx.x;
        float s = 0.f;
        #pragma unroll
        for (int d = 0; d < DSUB; d++) s += Cs[k*DSUB + d] * Cs[k*DSUB + d];
        CC[k] = s;
    }
    __syncthreads();

    int p  = blockIdx.x * 256 + threadIdx.x;
    int s_ = p & (SEQ - 1);
    int bh = p >> 10;
    int b  = bh >> 3, h = bh & 7;
    const float* x = X + (size_t)(b*SEQ + s_) * ldx + h*HDIM + m*DSUB;

    float xv[DSUB], xx = 0.f;
    #pragma unroll
    for (int d = 0; d < DSUB; d++) { xv[d] = x[d]; xx += xv[d]*xv[d]; }

    float best = INFINITY; int bk = 0;
    for (int k = 0; k < KSUB; k++) {
        float dot = 0.f;
        #pragma unroll
        for (int d = 0; d < DSUB; d++) dot += xv[d] * Cs[k*DSUB + d];
        float d2 = xx + CC[k] - 2.f * dot;
        if (d2 < best) { best = d2; bk = k; }
    }

    __hip_bfloat16* r = rec + (size_t)(b*SEQ + s_) * (NKV*HDIM) + h*HDIM + m*DSUB;
    #pragma unroll
    for (int d = 0; d < DSUB; d++) r[d] = __float2bfloat16(Cs[bk*DSUB + d]);
}

// ---------------------------------------------------------------------------
// MFMA flash attention; output fp16 (feeds the f16 O-proj directly).
// ---------------------------------------------------------------------------
__global__ __launch_bounds__(256) void attn_mfma(
    const short* __restrict__ Qbf, const short* __restrict__ K,
    const short* __restrict__ V, _Float16* __restrict__ O)
{
    __shared__ short Ks[32 * 128];
    __shared__ short Vt[128 * 40];
    __shared__ short Ps[4 * 16 * 40];

    const int tid  = threadIdx.x;
    const int wid  = tid >> 6, lane = tid & 63;
    const int l15  = lane & 15, l4 = lane >> 4;
    const int qt   = gridDim.x - 1 - blockIdx.x;
    const int qb   = qt * 64;
    const int h    = blockIdx.y & 31, b = blockIdx.y >> 5;
    const int kvh  = h >> 2;
    const int qw   = qb + wid * 16;

    bf16x8 qf[4];
    {
        const short* qp = Qbf + (size_t)(b*SEQ + qw + l15) * 4096 + h*HDIM + l4*8;
        #pragma unroll
        for (int ks = 0; ks < 4; ks++) qf[ks] = *(const bf16x8*)(qp + 32*ks);
    }

    f32x4 o[8];
    #pragma unroll
    for (int i = 0; i < 8; i++) o[i] = (f32x4)0.f;
    float m[4]  = {-1e30f, -1e30f, -1e30f, -1e30f};
    float ls[4] = {0.f, 0.f, 0.f, 0.f};

    const int ntiles = 2 * (qt + 1);
    const short* Kg = K + (size_t)b * SEQ * 1024 + kvh * HDIM;
    const short* Vg = V + (size_t)b * SEQ * 1024 + kvh * HDIM;

    for (int t = 0; t < ntiles; t++) {
        const int jbase = t * 32;
        __syncthreads();
        {
            int j = tid >> 3, d0 = (tid & 7) * 16;
            const short* src = Kg + (size_t)(jbase + j) * 1024 + d0;
            bf16x8 a = *(const bf16x8*)src;
            bf16x8 c = *(const bf16x8*)(src + 8);
            int sw = (j & 7) << 3;
            *(bf16x8*)(Ks + j*128 + (d0 ^ sw))       = a;
            *(bf16x8*)(Ks + j*128 + ((d0 + 8) ^ sw)) = c;
        }
        {
            int j = tid & 31, e0 = (tid >> 5) * 16;
            const short* src = Vg + (size_t)(jbase + j) * 1024 + e0;
            bf16x8 a = *(const bf16x8*)src;
            bf16x8 c = *(const bf16x8*)(src + 8);
            #pragma unroll
            for (int i = 0; i < 8; i++) {
                Vt[(e0 + i)     * 40 + j] = a[i];
                Vt[(e0 + i + 8) * 40 + j] = c[i];
            }
        }
        __syncthreads();

        if (jbase >= qw + 16) continue;

        f32x4 sc0 = (f32x4)0.f, sc1 = (f32x4)0.f;
        #pragma unroll
        for (int ks = 0; ks < 4; ks++) {
            int d0 = 32*ks + l4*8;
            int j0 = l15, j1 = l15 + 16;
            bf16x8 kb0 = *(const bf16x8*)(Ks + j0*128 + (d0 ^ ((j0 & 7) << 3)));
            bf16x8 kb1 = *(const bf16x8*)(Ks + j1*128 + (d0 ^ ((j1 & 7) << 3)));
            sc0 = __builtin_amdgcn_mfma_f32_16x16x32_bf16(qf[ks], kb0, sc0, 0, 0, 0);
            sc1 = __builtin_amdgcn_mfma_f32_16x16x32_bf16(qf[ks], kb1, sc1, 0, 0, 0);
        }

        float mx[4];
        #pragma unroll
        for (int r = 0; r < 4; r++) {
            int q_r = qw + l4*4 + r;
            if (jbase + l15      > q_r) sc0[r] = -1e30f;
            if (jbase + 16 + l15 > q_r) sc1[r] = -1e30f;
            mx[r] = fmaxf(sc0[r], sc1[r]);
        }
        #pragma unroll
        for (int off = 1; off < 16; off <<= 1)
            #pragma unroll
            for (int r = 0; r < 4; r++)
                mx[r] = fmaxf(mx[r], __shfl_xor(mx[r], off, 64));

        #pragma unroll
        for (int r = 0; r < 4; r++) {
            float mn = fmaxf(m[r], mx[r]);
            float cf = __expf(m[r] - mn);
            m[r] = mn;
            float p0 = __expf(sc0[r] - mn);
            float p1 = __expf(sc1[r] - mn);
            ls[r] = ls[r] * cf + p0 + p1;
            #pragma unroll
            for (int dt = 0; dt < 8; dt++) o[dt][r] *= cf;
            Ps[wid*640 + (l4*4 + r)*40 + l15]      = f2bf(p0);
            Ps[wid*640 + (l4*4 + r)*40 + l15 + 16] = f2bf(p1);
        }

        bf16x8 pa = *(const bf16x8*)(Ps + wid*640 + l15*40 + l4*8);
        #pragma unroll
        for (int dt = 0; dt < 8; dt++) {
            bf16x8 vb = *(const bf16x8*)(Vt + (16*dt + l15)*40 + l4*8);
            o[dt] = __builtin_amdgcn_mfma_f32_16x16x32_bf16(pa, vb, o[dt], 0, 0, 0);
        }
    }

    #pragma unroll
    for (int off = 1; off < 16; off <<= 1)
        #pragma unroll
        for (int r = 0; r < 4; r++)
            ls[r] += __shfl_xor(ls[r], off, 64);

    _Float16* Op = O + (size_t)(b*SEQ + qw + l4*4) * 4096 + h*HDIM + l15;
    #pragma unroll
    for (int r = 0; r < 4; r++) {
        float inv = 1.f / ls[r];
        #pragma unroll
        for (int dt = 0; dt < 8; dt++)
            Op[(size_t)r * 4096 + dt * 16] = (_Float16)(o[dt][r] * inv);
    }
}

// ---------------------------------------------------------------------------
extern "C" void kernel_launch(void* const* d_in, const int* in_sizes, int n_in,
                              void* d_out, int out_size, void* d_ws, size_t ws_size,
                              hipStream_t stream)
{
    const float* hs  = (const float*)d_in[0];
    const float* q_w = (const float*)d_in[1];
    const float* q_b = (const float*)d_in[2];
    const float* k_w = (const float*)d_in[3];
    const float* k_b = (const float*)d_in[4];
    const float* v_w = (const float*)d_in[5];
    const float* v_b = (const float*)d_in[6];
    const float* o_w = (const float*)d_in[7];
    const float* k_c = (const float*)d_in[8];
    const float* v_c = (const float*)d_in[9];
    float* out = (float*)d_out;

    // Workspace overlay (peak 96.5 MiB), MiB offsets by phase:
    //  KV:    hs_hi[0,16) hs_mid[16,32) kvw_hi[32,48) kvw_mid[48,64)
    //         KVp[64,96) (KVf aliases KVp0=[64,80)) trig[96,96.5)
    //  Q:     qw_f16[32,64) (kvw dead)  Qbf[16,32) (hs_mid dead)
    //  PQ:    Krec[80,84) Vrec[84,88) (KVp1 dead)
    //  attn:  AttnH[32,48) (qw dead)  ow_f16[48,80) (KVf dead after pq)
    char* ws = (char*)d_ws;
    _Float16*       hs_hi  = (_Float16*)(ws);
    _Float16*       hs_mid = (_Float16*)(ws + 16777216);
    _Float16*       kvw_hi = (_Float16*)(ws + 33554432);
    _Float16*       kvw_mid= (_Float16*)(ws + 50331648);
    float*          KVp    = (float*)(ws + 67108864);     // [2][2048][2048]
    float*          KVf    = (float*)(ws + 67108864);     // aliases KVp0
    __hip_bfloat16* Krec   = (__hip_bfloat16*)(ws + 83886080);
    __hip_bfloat16* Vrec   = (__hip_bfloat16*)(ws + 88080384);
    float*          cosT   = (float*)(ws + 100663296);
    float*          sinT   = (float*)(ws + 100925440);
    _Float16*       qw_f16 = (_Float16*)(ws + 33554432);
    __hip_bfloat16* Qbf    = (__hip_bfloat16*)(ws + 16777216);
    _Float16*       AttnH  = (_Float16*)(ws + 33554432);
    _Float16*       ow_f16 = (_Float16*)(ws + 50331648);

    rope_table<<<dim3(256), dim3(256), 0, stream>>>(cosT, sinT);

    // splits: hs (2048x4096), k_w/v_w stacked into kvw (2048x4096)
    split_f16<<<dim3(4096), 256, 0, stream>>>(hs, hs_hi, hs_mid, 1048576);
    split_f16<<<dim3(2048), 256, 0, stream>>>(k_w, kvw_hi, kvw_mid, 524288);
    split_f16<<<dim3(2048), 256, 0, stream>>>(v_w, kvw_hi + (size_t)1024*4096,
                                              kvw_mid + (size_t)1024*4096, 524288);

    // fused K|V projection: split-K=2 partials, then reduce + bias + K-rope
    gemm_kv_3p<<<dim3(16, 16, 2), 256, 0, stream>>>(hs_hi, hs_mid, kvw_hi, kvw_mid, KVp);
    kv_reduce<<<dim3(4096, 2), 256, 0, stream>>>(KVp, k_b, v_b, cosT, sinT);

    // Q projection with fused rope+scale+bf16 (kvw dead -> qw; hs_mid dead -> Qbf)
    cast_f16<<<dim3(8192), 256, 0, stream>>>(q_w, qw_f16, 2097152);
    gemm_q_rope<<<dim3(32, 16), 256, 0, stream>>>(hs_hi, qw_f16, q_b, Qbf, cosT, sinT);

    // PQ round-trips (KVp1 dead -> Krec/Vrec)
    pq_kernel<<<dim3(64, PQM), 256, 0, stream>>>(KVf,        k_c, Krec, 2048);
    pq_kernel<<<dim3(64, PQM), 256, 0, stream>>>(KVf + 1024, v_c, Vrec, 2048);

    // O weights (qw upper + KVf dead -> ow)
    cast_f16<<<dim3(8192), 256, 0, stream>>>(o_w, ow_f16, 2097152);

    // attention (qw dead -> AttnH)
    attn_mfma<<<dim3(16, 64), 256, 0, stream>>>((const short*)Qbf, (const short*)Krec,
                                                (const short*)Vrec, AttnH);

    // O projection
    gemm_f16_1p<<<dim3(32, 16), 256, 0, stream>>>(AttnH, ow_f16, out, NH*HDIM, 4096);
}

// Round 6
// 531.230 us; speedup vs baseline: 10.4947x; 1.0437x over previous
//
#include <hip/hip_runtime.h>
#include <hip/hip_bf16.h>
#include <math.h>

#define NH   32
#define NKV  8
#define HDIM 128
#define BATCH 2
#define SEQ  1024
#define KSUB 256
#define DSUB 16
#define PQM  8

typedef __attribute__((ext_vector_type(8))) _Float16 f16x8;
typedef __attribute__((ext_vector_type(8))) short bf16x8;
typedef __attribute__((ext_vector_type(4))) short bf16x4;
typedef __attribute__((ext_vector_type(4))) float f32x4;
typedef __attribute__((address_space(3))) short lds_short;

__device__ inline short f2bf(float x) {
    unsigned u = __builtin_bit_cast(unsigned, x);
    unsigned r = (u + 0x7fff + ((u >> 16) & 1)) >> 16;
    return (short)r;
}

__device__ inline void gload_lds16(const void* g, void* l) {
    __builtin_amdgcn_global_load_lds(
        (const __attribute__((address_space(1))) unsigned*)g,
        (__attribute__((address_space(3))) unsigned*)l, 16, 0, 0);
}

// ds_read_b64_tr_b16: lane l, elem e reads lds[(l&15) + e*16 + (l>>4)*64]
// relative to the 16-lane group's tile when addr_l = base + l*8 bytes.
__device__ inline bf16x4 tr16(unsigned byte_addr) {
    bf16x4 r;
    asm volatile("ds_read_b64_tr_b16 %0, %1" : "=v"(r) : "v"(byte_addr));
    return r;
}

// ---------------------------------------------------------------------------
// fp32 -> fp16 2-term split, 8 elems/thread: x = hi + mid * 2^-12.
// ---------------------------------------------------------------------------
__global__ void split_f16(const float* __restrict__ x,
                          _Float16* __restrict__ hi, _Float16* __restrict__ mid,
                          int n8)
{
    int i = blockIdx.x * 256 + threadIdx.x;
    if (i < n8) {
        float4 v0 = ((const float4*)x)[2*i];
        float4 v1 = ((const float4*)x)[2*i + 1];
        float v[8] = {v0.x, v0.y, v0.z, v0.w, v1.x, v1.y, v1.z, v1.w};
        f16x8 h, m;
        #pragma unroll
        for (int j = 0; j < 8; j++) {
            _Float16 hh = (_Float16)v[j];
            h[j] = hh;
            m[j] = (_Float16)((v[j] - (float)hh) * 4096.f);
        }
        ((f16x8*)hi)[i]  = h;
        ((f16x8*)mid)[i] = m;
    }
}

__global__ void cast_f16(const float* __restrict__ x, _Float16* __restrict__ y, int n8)
{
    int i = blockIdx.x * 256 + threadIdx.x;
    if (i < n8) {
        float4 v0 = ((const float4*)x)[2*i];
        float4 v1 = ((const float4*)x)[2*i + 1];
        float v[8] = {v0.x, v0.y, v0.z, v0.w, v1.x, v1.y, v1.z, v1.w};
        f16x8 h;
        #pragma unroll
        for (int j = 0; j < 8; j++) h[j] = (_Float16)v[j];
        ((f16x8*)y)[i] = h;
    }
}

// ---------------------------------------------------------------------------
// KV projection, 3-pass precision-split, split-K=2. (unchanged)
// ---------------------------------------------------------------------------
__global__ __launch_bounds__(256, 2) void gemm_kv_3p(
    const _Float16* __restrict__ Ahi, const _Float16* __restrict__ Ami,
    const _Float16* __restrict__ Whi, const _Float16* __restrict__ Wmi,
    float* __restrict__ Cp)
{
    __shared__ _Float16 sAh[128 * 32];
    __shared__ _Float16 sAm[128 * 32];
    __shared__ _Float16 sWh[128 * 32];
    __shared__ _Float16 sWm[128 * 32];

    const int tid = threadIdx.x;
    const int wid = tid >> 6, lane = tid & 63;
    const int l15 = lane & 15, l4 = lane >> 4;
    const int col0 = blockIdx.x * 128, row0 = blockIdx.y * 128;
    const int kz = blockIdx.z;
    const int wr = (wid >> 1) * 64, wc = (wid & 1) * 64;

    f32x4 am[4][4], ax[4][4];
    #pragma unroll
    for (int m = 0; m < 4; m++)
        #pragma unroll
        for (int n = 0; n < 4; n++) { am[m][n] = (f32x4)0.f; ax[m][n] = (f32x4)0.f; }

    const int ci0 = tid, ci1 = tid + 256;
    const size_t kb = (size_t)kz * 2048;
    const _Float16* pAh0 = Ahi + (size_t)(row0 + (ci0 >> 2)) * 4096 + kb + (ci0 & 3) * 8;
    const _Float16* pAh1 = Ahi + (size_t)(row0 + (ci1 >> 2)) * 4096 + kb + (ci1 & 3) * 8;
    const _Float16* pAm0 = Ami + (size_t)(row0 + (ci0 >> 2)) * 4096 + kb + (ci0 & 3) * 8;
    const _Float16* pAm1 = Ami + (size_t)(row0 + (ci1 >> 2)) * 4096 + kb + (ci1 & 3) * 8;
    const _Float16* pWh0 = Whi + (size_t)(col0 + (ci0 >> 2)) * 4096 + kb + (ci0 & 3) * 8;
    const _Float16* pWh1 = Whi + (size_t)(col0 + (ci1 >> 2)) * 4096 + kb + (ci1 & 3) * 8;
    const _Float16* pWm0 = Wmi + (size_t)(col0 + (ci0 >> 2)) * 4096 + kb + (ci0 & 3) * 8;
    const _Float16* pWm1 = Wmi + (size_t)(col0 + (ci1 >> 2)) * 4096 + kb + (ci1 & 3) * 8;

    for (int k0 = 0; k0 < 2048; k0 += 32) {
        __syncthreads();
        gload_lds16(pAh0 + k0, sAh + ci0 * 8);
        gload_lds16(pAh1 + k0, sAh + ci1 * 8);
        gload_lds16(pAm0 + k0, sAm + ci0 * 8);
        gload_lds16(pAm1 + k0, sAm + ci1 * 8);
        gload_lds16(pWh0 + k0, sWh + ci0 * 8);
        gload_lds16(pWh1 + k0, sWh + ci1 * 8);
        gload_lds16(pWm0 + k0, sWm + ci0 * 8);
        gload_lds16(pWm1 + k0, sWm + ci1 * 8);
        __syncthreads();

        f16x8 ah[4], amv[4], bh[4], bm[4];
        #pragma unroll
        for (int m = 0; m < 4; m++) {
            ah[m]  = *(const f16x8*)(sAh + (wr + m*16 + l15) * 32 + l4 * 8);
            amv[m] = *(const f16x8*)(sAm + (wr + m*16 + l15) * 32 + l4 * 8);
        }
        #pragma unroll
        for (int n = 0; n < 4; n++) {
            bh[n] = *(const f16x8*)(sWh + (wc + n*16 + l15) * 32 + l4 * 8);
            bm[n] = *(const f16x8*)(sWm + (wc + n*16 + l15) * 32 + l4 * 8);
        }
        #pragma unroll
        for (int m = 0; m < 4; m++)
            #pragma unroll
            for (int n = 0; n < 4; n++) {
                am[m][n] = __builtin_amdgcn_mfma_f32_16x16x32_f16(ah[m],  bh[n], am[m][n], 0, 0, 0);
                ax[m][n] = __builtin_amdgcn_mfma_f32_16x16x32_f16(ah[m],  bm[n], ax[m][n], 0, 0, 0);
                ax[m][n] = __builtin_amdgcn_mfma_f32_16x16x32_f16(amv[m], bh[n], ax[m][n], 0, 0, 0);
            }
    }

    float* base = Cp + (size_t)kz * 2048 * 2048;
    const float s = 1.f / 4096.f;
    #pragma unroll
    for (int m = 0; m < 4; m++) {
        #pragma unroll
        for (int r = 0; r < 4; r++) {
            float* p = base + (size_t)(row0 + wr + m*16 + l4*4 + r) * 2048 + col0 + wc + l15;
            #pragma unroll
            for (int n = 0; n < 4; n++)
                p[n * 16] = am[m][n][r] + ax[m][n][r] * s;
        }
    }
}

// ---------------------------------------------------------------------------
// Split-K reduce + bias, fused K-RoPE. (unchanged)
// ---------------------------------------------------------------------------
__global__ void kv_reduce(float* __restrict__ KVp,
                          const float* __restrict__ bK, const float* __restrict__ bV,
                          const float* __restrict__ cosT, const float* __restrict__ sinT)
{
    int t = blockIdx.x * 256 + threadIdx.x;
    float* P0 = KVp;
    const float* P1 = KVp + (size_t)2048 * 2048;
    if (blockIdx.y == 0) {
        int i  = t & 63;
        int h  = (t >> 6) & 7;
        int rr = t >> 9;
        int s  = rr & (SEQ - 1);
        size_t o = (size_t)rr * 2048 + h * 128 + i;
        float x1 = P0[o]      + P1[o]      + bK[h*128 + i];
        float x2 = P0[o + 64] + P1[o + 64] + bK[h*128 + i + 64];
        float c  = cosT[s*64 + i];
        float sv = sinT[s*64 + i];
        P0[o]      = x1 * c - x2 * sv;
        P0[o + 64] = x2 * c + x1 * sv;
    } else {
        int j  = t & 511;
        int rr = t >> 9;
        size_t o = (size_t)rr * 2048 + 1024 + j;
        P0[o]       = P0[o]       + P1[o]       + bV[j];
        P0[o + 512] = P0[o + 512] + P1[o + 512] + bV[j + 512];
    }
}

// ---------------------------------------------------------------------------
// Q projection with fused RoPE + scale + bf16 output. (unchanged)
// ---------------------------------------------------------------------------
__global__ __launch_bounds__(256) void gemm_q_rope(
    const _Float16* __restrict__ A, const _Float16* __restrict__ W,
    const float* __restrict__ bias, __hip_bfloat16* __restrict__ Qbf,
    const float* __restrict__ cosT, const float* __restrict__ sinT)
{
    __shared__ _Float16 Al[128 * 32];
    __shared__ _Float16 Bl[128 * 32];

    const int tid = threadIdx.x;
    const int wid = tid >> 6, lane = tid & 63;
    const int l15 = lane & 15, l4 = lane >> 4;
    const int row0 = blockIdx.y * 128, col0 = blockIdx.x * 128;
    const int wr = (wid >> 1) * 64, wc = (wid & 1) * 32;
    const int K = 4096;

    f32x4 acc[4][4];
    #pragma unroll
    for (int m = 0; m < 4; m++)
        #pragma unroll
        for (int n = 0; n < 4; n++) acc[m][n] = (f32x4)0.f;

    const int ci0 = tid, ci1 = tid + 256;
    const _Float16* Ag0 = A + (size_t)(row0 + (ci0 >> 2)) * K + (ci0 & 3) * 8;
    const _Float16* Ag1 = A + (size_t)(row0 + (ci1 >> 2)) * K + (ci1 & 3) * 8;
    const _Float16* Wg0 = W + (size_t)(col0 + (ci0 >> 2)) * K + (ci0 & 3) * 8;
    const _Float16* Wg1 = W + (size_t)(col0 + (ci1 >> 2)) * K + (ci1 & 3) * 8;

    for (int k0 = 0; k0 < K; k0 += 32) {
        __syncthreads();
        gload_lds16(Ag0 + k0, Al + ci0 * 8);
        gload_lds16(Ag1 + k0, Al + ci1 * 8);
        gload_lds16(Wg0 + k0, Bl + ci0 * 8);
        gload_lds16(Wg1 + k0, Bl + ci1 * 8);
        __syncthreads();

        f16x8 af[4], bfr[4];
        #pragma unroll
        for (int m = 0; m < 4; m++)
            af[m] = *(const f16x8*)(Al + (wr + m*16 + l15) * 32 + l4 * 8);
        #pragma unroll
        for (int n = 0; n < 4; n++) {
            int fc = wc + (n & 1) * 16 + (n >> 1) * 64;
            bfr[n] = *(const f16x8*)(Bl + (fc + l15) * 32 + l4 * 8);
        }
        #pragma unroll
        for (int m = 0; m < 4; m++)
            #pragma unroll
            for (int n = 0; n < 4; n++)
                acc[m][n] = __builtin_amdgcn_mfma_f32_16x16x32_f16(af[m], bfr[n], acc[m][n], 0, 0, 0);
    }

    const float scale = 0.08838834764831845f;
    #pragma unroll
    for (int m = 0; m < 4; m++) {
        #pragma unroll
        for (int r = 0; r < 4; r++) {
            int rr = row0 + wr + m*16 + l4*4 + r;
            int s  = rr & (SEQ - 1);
            #pragma unroll
            for (int n = 0; n < 2; n++) {
                int i = wc + n*16 + l15;
                float x1 = acc[m][n][r]     + bias[col0 + i];
                float x2 = acc[m][n + 2][r] + bias[col0 + i + 64];
                float c  = cosT[s*64 + i];
                float sv = sinT[s*64 + i];
                Qbf[(size_t)rr * 4096 + col0 + i]      = __float2bfloat16((x1*c - x2*sv) * scale);
                Qbf[(size_t)rr * 4096 + col0 + i + 64] = __float2bfloat16((x2*c + x1*sv) * scale);
            }
        }
    }
}

// ---------------------------------------------------------------------------
// 1-pass fp16 MFMA GEMM (O projection). (unchanged)
// ---------------------------------------------------------------------------
__global__ __launch_bounds__(256) void gemm_f16_1p(
    const _Float16* __restrict__ A, const _Float16* __restrict__ W,
    float* __restrict__ C, int N, int K)
{
    __shared__ _Float16 Al[128 * 32];
    __shared__ _Float16 Bl[128 * 32];

    const int tid = threadIdx.x;
    const int wid = tid >> 6, lane = tid & 63;
    const int l15 = lane & 15, l4 = lane >> 4;
    const int row0 = blockIdx.y * 128, col0 = blockIdx.x * 128;
    const int wr = (wid >> 1) * 64, wc = (wid & 1) * 64;

    f32x4 acc[4][4];
    #pragma unroll
    for (int m = 0; m < 4; m++)
        #pragma unroll
        for (int n = 0; n < 4; n++) acc[m][n] = (f32x4)0.f;

    const int ci0 = tid, ci1 = tid + 256;
    const _Float16* Ag0 = A + (size_t)(row0 + (ci0 >> 2)) * K + (ci0 & 3) * 8;
    const _Float16* Ag1 = A + (size_t)(row0 + (ci1 >> 2)) * K + (ci1 & 3) * 8;
    const _Float16* Wg0 = W + (size_t)(col0 + (ci0 >> 2)) * K + (ci0 & 3) * 8;
    const _Float16* Wg1 = W + (size_t)(col0 + (ci1 >> 2)) * K + (ci1 & 3) * 8;

    for (int k0 = 0; k0 < K; k0 += 32) {
        __syncthreads();
        gload_lds16(Ag0 + k0, Al + ci0 * 8);
        gload_lds16(Ag1 + k0, Al + ci1 * 8);
        gload_lds16(Wg0 + k0, Bl + ci0 * 8);
        gload_lds16(Wg1 + k0, Bl + ci1 * 8);
        __syncthreads();

        f16x8 af[4], bfr[4];
        #pragma unroll
        for (int m = 0; m < 4; m++)
            af[m] = *(const f16x8*)(Al + (wr + m*16 + l15) * 32 + l4 * 8);
        #pragma unroll
        for (int n = 0; n < 4; n++)
            bfr[n] = *(const f16x8*)(Bl + (wc + n*16 + l15) * 32 + l4 * 8);
        #pragma unroll
        for (int m = 0; m < 4; m++)
            #pragma unroll
            for (int n = 0; n < 4; n++)
                acc[m][n] = __builtin_amdgcn_mfma_f32_16x16x32_f16(af[m], bfr[n], acc[m][n], 0, 0, 0);
    }

    #pragma unroll
    for (int m = 0; m < 4; m++) {
        #pragma unroll
        for (int r = 0; r < 4; r++) {
            float* Cp = C + (size_t)(row0 + wr + m*16 + l4*4 + r) * N + col0 + wc + l15;
            #pragma unroll
            for (int n = 0; n < 4; n++)
                Cp[n * 16] = acc[m][n][r];
        }
    }
}

// ---------------------------------------------------------------------------
__global__ void rope_table(float* __restrict__ cosT, float* __restrict__ sinT)
{
    int idx = blockIdx.x * 256 + threadIdx.x;
    int s = idx >> 6, i = idx & 63;
    float inv_f = (float)pow(1.0e6, -(double)i / 64.0);
    float freq  = (float)s * inv_f;
    cosT[idx] = (float)cos((double)freq);
    sinT[idx] = (float)sin((double)freq);
}

// ---------------------------------------------------------------------------
// PQ round-trip (fp32-exact distances). (unchanged)
// ---------------------------------------------------------------------------
__global__ __launch_bounds__(256) void pq_kernel(
    const float* __restrict__ X, const float* __restrict__ cent,
    __hip_bfloat16* __restrict__ rec, int ldx)
{
    __shared__ float Cs[KSUB * DSUB];
    __shared__ float CC[KSUB];
    const int m = blockIdx.y;
    const float* cm = cent + (size_t)m * KSUB * DSUB;
    for (int t = threadIdx.x; t < KSUB * DSUB; t += 256) Cs[t] = cm[t];
    __syncthreads();
    {
        int k = threadIdx.x;
        float s = 0.f;
        #pragma unroll
        for (int d = 0; d < DSUB; d++) s += Cs[k*DSUB + d] * Cs[k*DSUB + d];
        CC[k] = s;
    }
    __syncthreads();

    int p  = blockIdx.x * 256 + threadIdx.x;
    int s_ = p & (SEQ - 1);
    int bh = p >> 10;
    int b  = bh >> 3, h = bh & 7;
    const float* x = X + (size_t)(b*SEQ + s_) * ldx + h*HDIM + m*DSUB;

    float xv[DSUB], xx = 0.f;
    #pragma unroll
    for (int d = 0; d < DSUB; d++) { xv[d] = x[d]; xx += xv[d]*xv[d]; }

    float best = INFINITY; int bk = 0;
    for (int k = 0; k < KSUB; k++) {
        float dot = 0.f;
        #pragma unroll
        for (int d = 0; d < DSUB; d++) dot += xv[d] * Cs[k*DSUB + d];
        float d2 = xx + CC[k] - 2.f * dot;
        if (d2 < best) { best = d2; bk = k; }
    }

    __hip_bfloat16* r = rec + (size_t)(b*SEQ + s_) * (NKV*HDIM) + h*HDIM + m*DSUB;
    #pragma unroll
    for (int d = 0; d < DSUB; d++) r[d] = __float2bfloat16(Cs[bk*DSUB + d]);
}

// ---------------------------------------------------------------------------
// MFMA flash attention, v2: KVBLK=64, double-buffered global_load_lds staging
// (K with inverse-XOR-swizzled source; V in 4x16-subtiled layout consumed via
// ds_read_b64_tr_b16 with a matched k-permutation on the P operand).
// ---------------------------------------------------------------------------
__global__ __launch_bounds__(256) void attn_mfma(
    const short* __restrict__ K, const short* __restrict__ V,
    const short* __restrict__ Qbf, _Float16* __restrict__ O)
{
    __shared__ short Ks[2][64 * 128];   // row j: d stored at (d ^ ((j&7)<<3))
    __shared__ short Vs[2][64 * 128];   // addr = (d>>4)*1024 + (j>>2)*64 + (j&3)*16 + (d&15)
    __shared__ short Ps[4][16 * 72];    // per-wave P [q][j], stride 72

    const int tid = threadIdx.x;
    const int wid = tid >> 6, lane = tid & 63;
    const int l15 = lane & 15, l4 = lane >> 4;
    const int qt  = gridDim.x - 1 - blockIdx.x;     // heaviest blocks first
    const int qb  = qt * 64;
    const int h   = blockIdx.y & 31, b = blockIdx.y >> 5;
    const int kvh = h >> 2;
    const int qw  = qb + wid * 16;

    // Q fragments
    bf16x8 qf[4];
    {
        const short* qp = Qbf + (size_t)(b*SEQ + qw + l15) * 4096 + h*HDIM + l4*8;
        #pragma unroll
        for (int ks = 0; ks < 4; ks++) qf[ks] = *(const bf16x8*)(qp + 32*ks);
    }

    // static per-lane staging source offsets (granule g -> global (j,d))
    int offK[4], offV[4], ldsb[4];
    #pragma unroll
    for (int i = 0; i < 4; i++) {
        int g  = i*256 + wid*64 + lane;
        int jK = g >> 4;
        int dK = ((g & 15) << 3) ^ ((jK & 7) << 3);
        offK[i] = jK * 1024 + dK;
        int jV = ((g >> 3) & 15) * 4 + ((g >> 1) & 3);
        int dV = (g >> 7) * 16 + (g & 1) * 8;
        offV[i] = jV * 1024 + dV;
        ldsb[i] = (i*256 + wid*64) * 8;     // dest offset in shorts (uniform/wave)
    }

    const short* Kg = K + (size_t)b * SEQ * 1024 + kvh * HDIM;
    const short* Vg = V + (size_t)b * SEQ * 1024 + kvh * HDIM;

    f32x4 o[8];
    #pragma unroll
    for (int i = 0; i < 8; i++) o[i] = (f32x4)0.f;
    float m[4]  = {-1e30f, -1e30f, -1e30f, -1e30f};
    float ls[4] = {0.f, 0.f, 0.f, 0.f};

    const int nt = qt + 1;

    auto STAGE = [&](int jb, int bs) {
        const short* Kp = Kg + (size_t)jb * 1024;
        const short* Vp = Vg + (size_t)jb * 1024;
        #pragma unroll
        for (int i = 0; i < 4; i++) {
            gload_lds16(Kp + offK[i], &Ks[bs][0] + ldsb[i]);
            gload_lds16(Vp + offV[i], &Vs[bs][0] + ldsb[i]);
        }
    };

    STAGE(0, 0);
    asm volatile("s_waitcnt vmcnt(0)");
    __syncthreads();

    for (int t = 0; t < nt; t++) {
        const int jbase = t * 64;
        if (t + 1 < nt) STAGE(jbase + 64, (t + 1) & 1);

        if (jbase < qw + 16) {
            const short* Kb = Ks[t & 1];
            lds_short* v3 = (lds_short*)&Vs[t & 1][0];
            unsigned vB = (unsigned)(size_t)v3;

            // ---- QK^T: S[16q][64j] as four 16-col fragments
            f32x4 sc[4];
            #pragma unroll
            for (int n = 0; n < 4; n++) sc[n] = (f32x4)0.f;
            #pragma unroll
            for (int ks = 0; ks < 4; ks++) {
                int d0 = ks*32 + l4*8;
                #pragma unroll
                for (int n = 0; n < 4; n++) {
                    int j = n*16 + l15;
                    bf16x8 kb = *(const bf16x8*)(Kb + j*128 + (d0 ^ ((j & 7) << 3)));
                    sc[n] = __builtin_amdgcn_mfma_f32_16x16x32_bf16(qf[ks], kb, sc[n], 0, 0, 0);
                }
            }

            // ---- mask + online softmax + P -> per-wave LDS
            #pragma unroll
            for (int r = 0; r < 4; r++) {
                int q_r = qw + l4*4 + r;
                float mx = -1e30f;
                #pragma unroll
                for (int n = 0; n < 4; n++) {
                    if (jbase + n*16 + l15 > q_r) sc[n][r] = -1e30f;
                    mx = fmaxf(mx, sc[n][r]);
                }
                #pragma unroll
                for (int off = 1; off < 16; off <<= 1)
                    mx = fmaxf(mx, __shfl_xor(mx, off, 64));
                float mn = fmaxf(m[r], mx);
                float cf = __expf(m[r] - mn);
                m[r] = mn;
                float sum = 0.f;
                short* Pr = &Ps[wid][(l4*4 + r) * 72];
                #pragma unroll
                for (int n = 0; n < 4; n++) {
                    float pv = __expf(sc[n][r] - mn);
                    sum += pv;
                    Pr[n*16 + l15] = f2bf(pv);
                }
                ls[r] = ls[r] * cf + sum;
                #pragma unroll
                for (int dt = 0; dt < 8; dt++) o[dt][r] *= cf;
            }

            // ---- PV: O[16q][128d] += P[16x64] . V[64x128]
            // k-permutation: MFMA k-slot (l4,jj) holds j = ks2*32 + (jj>=4)*16 + l4*4 + (jj&3)
            // applied identically to A (P reads) and B (tr reads) -> dot invariant.
            #pragma unroll
            for (int ks2 = 0; ks2 < 2; ks2++) {
                const short* Pw = &Ps[wid][0];
                bf16x4 a0 = *(const bf16x4*)(Pw + l15*72 + ks2*32 + l4*4);
                bf16x4 a1 = *(const bf16x4*)(Pw + l15*72 + ks2*32 + 16 + l4*4);
                bf16x8 a;
                a[0]=a0[0]; a[1]=a0[1]; a[2]=a0[2]; a[3]=a0[3];
                a[4]=a1[0]; a[5]=a1[1]; a[6]=a1[2]; a[7]=a1[3];

                bf16x4 t1[8], t2[8];
                #pragma unroll
                for (int dt = 0; dt < 8; dt++) {
                    unsigned base = vB + (unsigned)((dt*1024 + ks2*512 + lane*4) * 2);
                    t1[dt] = tr16(base);
                    t2[dt] = tr16(base + 512);
                }
                asm volatile("s_waitcnt lgkmcnt(0)");
                __builtin_amdgcn_sched_barrier(0);
                #pragma unroll
                for (int dt = 0; dt < 8; dt++) {
                    bf16x8 bf;
                    bf[0]=t1[dt][0]; bf[1]=t1[dt][1]; bf[2]=t1[dt][2]; bf[3]=t1[dt][3];
                    bf[4]=t2[dt][0]; bf[5]=t2[dt][1]; bf[6]=t2[dt][2]; bf[7]=t2[dt][3];
                    o[dt] = __builtin_amdgcn_mfma_f32_16x16x32_bf16(a, bf, o[dt], 0, 0, 0);
                }
            }
        }

        asm volatile("s_waitcnt vmcnt(0)");
        __syncthreads();
    }

    // ---- denominator reduce + store
    #pragma unroll
    for (int off = 1; off < 16; off <<= 1)
        #pragma unroll
        for (int r = 0; r < 4; r++)
            ls[r] += __shfl_xor(ls[r], off, 64);

    _Float16* Op = O + (size_t)(b*SEQ + qw + l4*4) * 4096 + h*HDIM + l15;
    #pragma unroll
    for (int r = 0; r < 4; r++) {
        float inv = 1.f / ls[r];
        #pragma unroll
        for (int dt = 0; dt < 8; dt++)
            Op[(size_t)r * 4096 + dt * 16] = (_Float16)(o[dt][r] * inv);
    }
}

// ---------------------------------------------------------------------------
extern "C" void kernel_launch(void* const* d_in, const int* in_sizes, int n_in,
                              void* d_out, int out_size, void* d_ws, size_t ws_size,
                              hipStream_t stream)
{
    const float* hs  = (const float*)d_in[0];
    const float* q_w = (const float*)d_in[1];
    const float* q_b = (const float*)d_in[2];
    const float* k_w = (const float*)d_in[3];
    const float* k_b = (const float*)d_in[4];
    const float* v_w = (const float*)d_in[5];
    const float* v_b = (const float*)d_in[6];
    const float* o_w = (const float*)d_in[7];
    const float* k_c = (const float*)d_in[8];
    const float* v_c = (const float*)d_in[9];
    float* out = (float*)d_out;

    char* ws = (char*)d_ws;
    _Float16*       hs_hi  = (_Float16*)(ws);
    _Float16*       hs_mid = (_Float16*)(ws + 16777216);
    _Float16*       kvw_hi = (_Float16*)(ws + 33554432);
    _Float16*       kvw_mid= (_Float16*)(ws + 50331648);
    float*          KVp    = (float*)(ws + 67108864);     // [2][2048][2048]
    float*          KVf    = (float*)(ws + 67108864);     // aliases KVp0
    __hip_bfloat16* Krec   = (__hip_bfloat16*)(ws + 83886080);
    __hip_bfloat16* Vrec   = (__hip_bfloat16*)(ws + 88080384);
    float*          cosT   = (float*)(ws + 100663296);
    float*          sinT   = (float*)(ws + 100925440);
    _Float16*       qw_f16 = (_Float16*)(ws + 33554432);
    __hip_bfloat16* Qbf    = (__hip_bfloat16*)(ws + 16777216);
    _Float16*       AttnH  = (_Float16*)(ws + 33554432);
    _Float16*       ow_f16 = (_Float16*)(ws + 50331648);

    rope_table<<<dim3(256), dim3(256), 0, stream>>>(cosT, sinT);

    split_f16<<<dim3(4096), 256, 0, stream>>>(hs, hs_hi, hs_mid, 1048576);
    split_f16<<<dim3(2048), 256, 0, stream>>>(k_w, kvw_hi, kvw_mid, 524288);
    split_f16<<<dim3(2048), 256, 0, stream>>>(v_w, kvw_hi + (size_t)1024*4096,
                                              kvw_mid + (size_t)1024*4096, 524288);

    gemm_kv_3p<<<dim3(16, 16, 2), 256, 0, stream>>>(hs_hi, hs_mid, kvw_hi, kvw_mid, KVp);
    kv_reduce<<<dim3(4096, 2), 256, 0, stream>>>(KVp, k_b, v_b, cosT, sinT);

    cast_f16<<<dim3(8192), 256, 0, stream>>>(q_w, qw_f16, 2097152);
    gemm_q_rope<<<dim3(32, 16), 256, 0, stream>>>(hs_hi, qw_f16, q_b, Qbf, cosT, sinT);

    pq_kernel<<<dim3(64, PQM), 256, 0, stream>>>(KVf,        k_c, Krec, 2048);
    pq_kernel<<<dim3(64, PQM), 256, 0, stream>>>(KVf + 1024, v_c, Vrec, 2048);

    cast_f16<<<dim3(8192), 256, 0, stream>>>(o_w, ow_f16, 2097152);

    attn_mfma<<<dim3(16, 64), 256, 0, stream>>>((const short*)Krec, (const short*)Vrec,
                                                (const short*)Qbf, AttnH);

    gemm_f16_1p<<<dim3(32, 16), 256, 0, stream>>>(AttnH, ow_f16, out, NH*HDIM, 4096);
}